// Round 8
// baseline (249.841 us; speedup 1.0000x reference)
//
#include <hip/hip_runtime.h>
#include <cstdint>
#include <cstddef>

typedef unsigned long long ull;

#define KTOP   1000
#define CAP    4096      // candidate gather capacity per (b,c)
#define HBITS  14
#define HB     (1 << HBITS)          // 16384 histogram bins (top-14 float bits)
#define HSHIFT (32 - HBITS)
#define ROWS   1024      // padded rank capacity (>= KTOP)
#define WORDS  16        // 1024 / 64 bitmask words per row
#define HCHUNK 16        // score chunks per (b,c) for the LDS histogram kernel

// ---------------- Kernel 1: softmax + SSD decode (pure streaming) ----------------
__global__ void decode_kernel(const float* __restrict__ loc,
                              const float* __restrict__ conf,
                              const float* __restrict__ prior,
                              float* __restrict__ scores,   // [B*Cfg][P]
                              float* __restrict__ cs,       // [B][P][4] center-size
                              int B, int C, int P) {
#pragma clang fp contract(off)
    int t = blockIdx.x * blockDim.x + threadIdx.x;
    if (t >= B * P) return;
    int b = t / P;
    int p = t - b * P;

    // softmax over class dim (C small)
    float x[8];
    float m = -INFINITY;
    for (int c = 0; c < C; ++c) {
        x[c] = conf[((size_t)b * C + c) * P + p];
        m = fmaxf(m, x[c]);
    }
    float sum = 0.f;
    for (int c = 0; c < C; ++c) {
        x[c] = expf(x[c] - m);
        sum += x[c];
    }
    for (int c = 1; c < C; ++c) {
        float v = x[c] / sum;
        int bc = b * (C - 1) + (c - 1);
        scores[(size_t)bc * P + p] = v;
    }

    // decode
    float l0 = loc[((size_t)b * 4 + 0) * P + p];
    float l1 = loc[((size_t)b * 4 + 1) * P + p];
    float l2 = loc[((size_t)b * 4 + 2) * P + p];
    float l3 = loc[((size_t)b * 4 + 3) * P + p];
    float pcx = prior[(size_t)p * 4 + 0];
    float pcy = prior[(size_t)p * 4 + 1];
    float pw  = prior[(size_t)p * 4 + 2];
    float ph  = prior[(size_t)p * 4 + 3];

    float cx = pcx + (l0 * 0.1f) * pw;
    float cy = pcy + (l1 * 0.1f) * ph;
    float w  = pw * expf(l2 * 0.2f);
    float h  = ph * expf(l3 * 0.2f);

    size_t o = ((size_t)b * P + p) * 4;
    cs[o + 0] = cx;
    cs[o + 1] = cy;
    cs[o + 2] = w;
    cs[o + 3] = h;
}

// ---------------- Kernel 1b: LDS-privatized score histogram ----------------
__global__ void __launch_bounds__(256)
hist_kernel(const float* __restrict__ scores,
            const float* __restrict__ cthp,
            unsigned* __restrict__ hist,     // [NBC][HB]
            int P) {
    __shared__ unsigned sh[HB / 2];          // 32 KB (16-bit packed counters)
    int bc  = blockIdx.x;
    int tid = threadIdx.x;
    float cth = *cthp;

    for (int i = tid; i < HB / 2; i += 256) sh[i] = 0u;
    __syncthreads();

    int chunk = (P + HCHUNK - 1) / HCHUNK;
    int lo = blockIdx.y * chunk;
    int hi = lo + chunk; if (hi > P) hi = P;
    const float* s = scores + (size_t)bc * P;
    for (int p = lo + tid; p < hi; p += 256) {
        float v = s[p];
        if (v >= cth) {
            unsigned bin = __float_as_uint(v) >> HSHIFT;
            atomicAdd(&sh[bin >> 1], (bin & 1u) ? 65536u : 1u);
        }
    }
    __syncthreads();

    unsigned* h = hist + (size_t)bc * HB;
    for (int i = tid; i < HB / 2; i += 256) {
        unsigned v = sh[i];
        if (v & 0xFFFFu)  atomicAdd(&h[2 * i],     v & 0xFFFFu);
        if (v >> 16)      atomicAdd(&h[2 * i + 1], v >> 16);
    }
}

// ---------------- Kernel 2: per-(b,c) pivot bin via parallel suffix scan ----------------
__global__ void __launch_bounds__(256)
pivot_kernel(const unsigned* __restrict__ hist, unsigned* __restrict__ pivot) {
    int bc  = blockIdx.x;
    int t   = threadIdx.x;
    const unsigned* h = hist + (size_t)bc * HB;
    __shared__ unsigned T[256];

    const int per = HB / 256;                // 64 bins per thread
    int base = t * per;
    unsigned S = 0;
    for (int i = 0; i < per; ++i) S += h[base + i];
    T[t] = S;
    __syncthreads();

    for (int d = 1; d < 256; d <<= 1) {
        unsigned add = (t + d < 256) ? T[t + d] : 0u;
        __syncthreads();
        T[t] += add;
        __syncthreads();
    }

    unsigned Tt = T[t];
    unsigned Tn = (t + 1 < 256) ? T[t + 1] : 0u;
    if (Tt >= (unsigned)KTOP && Tn < (unsigned)KTOP) {
        unsigned cum = Tn;
        for (int i = per - 1; i >= 0; --i) {
            cum += h[base + i];
            if (cum >= (unsigned)KTOP) { pivot[bc] = (unsigned)(base + i); break; }
        }
    }
    if (t == 0 && T[0] < (unsigned)KTOP) pivot[bc] = 0u;   // fewer than KTOP valid: take all
}

// ---------------- Kernel 3: gather with BLOCK-aggregated allocation ----------------
__global__ void __launch_bounds__(256)
gather_kernel(const float* __restrict__ scores,
              const unsigned* __restrict__ pivot,
              unsigned* __restrict__ cnt,
              ull* __restrict__ cand,
              const float* __restrict__ cthp, int P) {
    __shared__ unsigned wsum[4];
    __shared__ unsigned s_base;
    int bc = blockIdx.x;
    const float* s = scores + (size_t)bc * P;
    float cth = *cthp;
    unsigned pv = pivot[bc];
    int nchunk = gridDim.y;
    int chunk = (P + nchunk - 1) / nchunk;
    int lo = blockIdx.y * chunk;
    int hi = lo + chunk; if (hi > P) hi = P;
    int tid  = threadIdx.x;
    int lane = tid & 63;
    int wid  = tid >> 6;

    // phase 1: count
    unsigned mycnt = 0;
    for (int p = lo + tid; p < hi; p += 256) {
        float v = s[p];
        unsigned k = __float_as_uint(v);
        if (v >= cth && (k >> HSHIFT) >= pv) ++mycnt;
    }
    unsigned x = mycnt;
    for (int d = 1; d < 64; d <<= 1) {
        unsigned y = (unsigned)__shfl_up((int)x, d);
        if (lane >= d) x += y;
    }
    if (lane == 63) wsum[wid] = x;
    __syncthreads();
    if (tid == 0) {
        unsigned tot = 0;
        for (int w = 0; w < 4; ++w) { unsigned t2 = wsum[w]; wsum[w] = tot; tot += t2; }
        s_base = tot ? atomicAdd(&cnt[bc], tot) : 0u;
    }
    __syncthreads();
    unsigned off = s_base + wsum[wid] + (x - mycnt);

    // phase 2: write (chunk is L2-hot from phase 1)
    ull* cb = cand + (size_t)bc * CAP;
    for (int p = lo + tid; p < hi; p += 256) {
        float v = s[p];
        unsigned k = __float_as_uint(v);
        if (v >= cth && (k >> HSHIFT) >= pv) {
            if (off < CAP)
                cb[off] = ((ull)k << 32) | (unsigned)(~(unsigned)p);
            ++off;
        }
    }
}

// ---------------- Kernel 4: per-(b,c) bitonic sort + export sorted boxes ----------------
__global__ void __launch_bounds__(1024)
sort_kernel(const ull* __restrict__ cand,
            const unsigned* __restrict__ cnt,
            const float* __restrict__ cs,
            float* __restrict__ rows,      // [NBC][KTOP][5] score,cx,cy,w,h
            float* __restrict__ bx1, float* __restrict__ by1,
            float* __restrict__ bx2, float* __restrict__ by2,
            float* __restrict__ bar,       // SoA [NBC][ROWS]
            int* __restrict__ nselArr,
            int P, int Cfg) {
#pragma clang fp contract(off)
    int bc  = blockIdx.x;
    int b   = bc / Cfg;
    int tid = threadIdx.x;
    __shared__ ull sbuf[CAP];

    int M = (int)cnt[bc]; if (M > CAP) M = CAP;
    int nsel = M < KTOP ? M : KTOP;
    if (tid == 0) nselArr[bc] = nsel;

    int n = 1024;
    while (n < M) n <<= 1;
    for (int i = tid; i < n; i += 1024)
        sbuf[i] = (i < M) ? cand[(size_t)bc * CAP + i] : 0ull;
    __syncthreads();

    for (unsigned k = 2; k <= (unsigned)n; k <<= 1) {
        for (unsigned j = k >> 1; j > 0; j >>= 1) {
            for (unsigned i = tid; i < (unsigned)n; i += 1024) {
                unsigned ixj = i ^ j;
                if (ixj > i) {
                    bool up = ((i & k) == 0u);
                    ull a = sbuf[i], bb = sbuf[ixj];
                    if ((a > bb) == up) { sbuf[i] = bb; sbuf[ixj] = a; }
                }
            }
            __syncthreads();
        }
    }

    for (int r = tid; r < nsel; r += 1024) {
        ull e = sbuf[n - 1 - r];
        float sc = __uint_as_float((unsigned)(e >> 32));
        int idx = (int)(~(unsigned)e);
        const float* c4 = cs + ((size_t)b * P + idx) * 4;
        float cx = c4[0], cy = c4[1], w = c4[2], h = c4[3];
        float x1 = cx - w / 2.f, y1 = cy - h / 2.f;
        float x2 = cx + w / 2.f, y2 = cy + h / 2.f;
        size_t sb = (size_t)bc * ROWS + r;
        bx1[sb] = x1; by1[sb] = y1; bx2[sb] = x2; by2[sb] = y2;
        bar[sb] = fmaxf(x2 - x1, 0.f) * fmaxf(y2 - y1, 0.f);
        float* rr = rows + ((size_t)bc * KTOP + r) * 5;
        rr[0] = sc; rr[1] = cx; rr[2] = cy; rr[3] = w; rr[4] = h;
    }
}

// ---------------- Kernel 5: GPU-wide suppression bitmask matrix ----------------
__global__ void __launch_bounds__(1024)
mask_kernel(const float* __restrict__ bx1, const float* __restrict__ by1,
            const float* __restrict__ bx2, const float* __restrict__ by2,
            const float* __restrict__ bar,
            const int* __restrict__ nselArr,
            const float* __restrict__ nthp,
            ull* __restrict__ mask) {       // [NBC][ROWS][WORDS]
#pragma clang fp contract(off)
    int bc   = blockIdx.x;
    int tile = blockIdx.y;                  // 16 tiles x 64 rows
    int tid  = threadIdx.x;
    int nsel = nselArr[bc];
    float nth = *nthp;

    __shared__ float sx1[ROWS], sy1[ROWS], sx2[ROWS], sy2[ROWS], sar[ROWS];
    size_t sb = (size_t)bc * ROWS;
    if (tid < nsel) {
        sx1[tid] = bx1[sb + tid]; sy1[tid] = by1[sb + tid];
        sx2[tid] = bx2[sb + tid]; sy2[tid] = by2[sb + tid];
        sar[tid] = bar[sb + tid];
    }
    __syncthreads();

    int i = tile * 64 + (tid >> 4);
    int w = tid & 15;
    if (i >= nsel) return;

    float xi1 = sx1[i], yi1 = sy1[i], xi2 = sx2[i], yi2 = sy2[i], ai = sar[i];
    ull bits = 0ull;
    int j0 = w << 6;
    for (int jj0 = 0; jj0 < 64; ++jj0) {
        int jj = (jj0 + (w << 2)) & 63;
        int j = j0 + jj;
        if (j > i && j < nsel) {
            float ww = fmaxf(fminf(xi2, sx2[j]) - fmaxf(xi1, sx1[j]), 0.f);
            float hh = fmaxf(fminf(yi2, sy2[j]) - fmaxf(yi1, sy1[j]), 0.f);
            float inter = ww * hh;
            float uni = ai + sar[j] - inter;
            float iou = inter / fmaxf(uni, 1e-12f);
            if (iou > nth) bits |= 1ull << jj;
        }
    }
    mask[(((size_t)bc * ROWS + i) << 4) + w] = bits;
}

// ---------------- Kernel 6: chunked serial bit-OR reduction + compact + write ----------------
// One wave per (b,c). LDS rows >= nsel are ZERO-PADDED at load (unconditional
// load + cndmask), making every loop constant-trip and fully unrollable:
// the 64 diagonal ds_reads hoist OFF the serial dependency chain (grouped
// issue, fine-grained lgkmcnt) — the chain is pure VALU. Padded ranks are
// no-ops (zero mask rows); the final `valid` mask cleans K.
__global__ void __launch_bounds__(64)
reduce_pack_kernel(const ull* __restrict__ mask,
                   const int* __restrict__ nselArr,
                   const float* __restrict__ rows,
                   float* __restrict__ out) {
    int bc   = blockIdx.x;
    int lane = threadIdx.x;                 // 64 threads = 1 wave
    int nsel = nselArr[bc];
    const ull* mrow = mask + ((size_t)bc * ROWS << 4);

    __shared__ ull sm[2048];                // 2 x (64 rows x 16 words) = 16 KB

    int nchunk = (nsel + 63) >> 6;          // <= 16
    ull S = 0ull;                           // lane w<16 holds suppressed-word w
    int g = lane >> 4;                      // row-group 0..3 for bulk apply
    int w = lane & 15;                      // word index for bulk apply
    int rsub = (lane >> 4);                 // sub-row within a k-load (4 rows/k)

    if (nchunk > 0) {
        ull r[16];
        // preload chunk 0, zero-padding rows >= nsel
        #pragma unroll
        for (int k = 0; k < 16; ++k) {
            int row = (k << 2) + rsub;
            ull v = mrow[k * 64 + lane];
            r[k] = (row < nsel) ? v : 0ull;
        }
        #pragma unroll
        for (int k = 0; k < 16; ++k) sm[k * 64 + lane] = r[k];

        for (int c = 0; c < nchunk; ++c) {
            int cb = (c & 1) << 10;
            int nb = ((c + 1) & 1) << 10;
            bool more = (c + 1) < nchunk;
            if (more) {
                #pragma unroll
                for (int k = 0; k < 16; ++k) {
                    int row = ((c + 1) << 6) + (k << 2) + rsub;
                    ull v = mrow[(size_t)(c + 1) * 1024 + k * 64 + lane];
                    r[k] = (row < nsel) ? v : 0ull;
                }
            }

            // ---- serial greedy on word c: constant 64 trips, fully unrolled ----
            // (padded ranks: di==0 -> cur unchanged; kbits garbage is harmless
            //  because the corresponding mask rows are zero and K is masked.)
            ull cur   = __shfl(S, c);
            ull kbits = 0ull;
            #pragma unroll
            for (int i = 0; i < 64; ++i) {
                ull di  = sm[cb + (i << 4) + c];     // hoisted off-chain by unroll
                ull sup = (cur >> i) & 1ull;
                cur   |= di & (sup - 1ull);
                kbits |= (sup ^ 1ull) << i;
            }

            // ---- bulk apply: lane (g,w) ORs kept rows of group g, word w ----
            unsigned sub = (unsigned)((kbits >> (g << 4)) & 0xFFFFull);
            int rbase2 = cb + (g << 8) + w;          // (g*16 rows) << 4 words
            ull part = 0ull;
            #pragma unroll
            for (int i = 0; i < 16; ++i) {
                ull v = sm[rbase2 + (i << 4)];       // unconditional, pipelined
                part |= v & (ull)(0ll - (long long)((sub >> i) & 1u));
            }
            part |= __shfl_xor(part, 16);
            part |= __shfl_xor(part, 32);
            S |= part;                               // lanes 0..15 meaningful
            if (lane == c) S = cur;                  // finalize word c

            if (more) {
                #pragma unroll
                for (int k = 0; k < 16; ++k) sm[nb + k * 64 + lane] = r[k];
            }
        }
    }

    // ---- kept bitmap -> compact positions -> write packed rows ----
    int base_i = lane << 6;
    ull valid = 0ull;
    if (lane < WORDS) {
        int rem = nsel - base_i;
        if (rem > 0) valid = (rem >= 64) ? ~0ull : ((1ull << rem) - 1ull);
    }
    ull K = (~S) & valid;
    int cpc = __popcll(K);
    int x = cpc;
    for (int d = 1; d < 64; d <<= 1) {
        int y = __shfl_up(x, d);
        if (lane >= d) x += y;
    }
    int pos = x - cpc;

    const float* rbase = rows + (size_t)bc * KTOP * 5;
    float* obase = out + (size_t)bc * KTOP * 5;
    for (int bit = 0; bit < 64; ++bit) {
        if ((K >> bit) & 1ull) {
            int i = base_i + bit;
            const float* rr = rbase + i * 5;
            float* oo = obase + pos * 5;
            oo[0] = rr[0]; oo[1] = rr[1]; oo[2] = rr[2]; oo[3] = rr[3]; oo[4] = rr[4];
            ++pos;
        }
    }
}

// ------------------------------- launcher -------------------------------
extern "C" void kernel_launch(void* const* d_in, const int* in_sizes, int n_in,
                              void* d_out, int out_size, void* d_ws, size_t ws_size,
                              hipStream_t stream) {
    (void)n_in; (void)ws_size;
    const float* loc   = (const float*)d_in[0];
    const float* conf  = (const float*)d_in[1];
    const float* prior = (const float*)d_in[2];
    const float* cth   = (const float*)d_in[3];
    const float* nth   = (const float*)d_in[4];
    float* out = (float*)d_out;

    int P   = in_sizes[2] / 4;
    int B   = in_sizes[0] / (4 * P);
    int C   = in_sizes[1] / (B * P);
    int Cfg = C - 1;
    int NBC = B * Cfg;

    // ---- carve workspace (256B aligned sections; 8B types first) ----
    char* base = (char*)d_ws;
    size_t off = 0;
    auto carve = [&](size_t bytes) { char* p = base + off; off = (off + bytes + 255) & ~(size_t)255; return p; };

    ull*      cand   = (ull*)     carve((size_t)NBC * CAP * 8);
    ull*      mask   = (ull*)     carve((size_t)NBC * ROWS * WORDS * 8);
    float*    scores = (float*)   carve((size_t)NBC * P * 4);
    float*    cs     = (float*)   carve((size_t)B * P * 4 * 4);
    float*    rows   = (float*)   carve((size_t)NBC * KTOP * 5 * 4);
    float*    bx1    = (float*)   carve((size_t)NBC * ROWS * 4);
    float*    by1    = (float*)   carve((size_t)NBC * ROWS * 4);
    float*    bx2    = (float*)   carve((size_t)NBC * ROWS * 4);
    float*    by2    = (float*)   carve((size_t)NBC * ROWS * 4);
    float*    bar    = (float*)   carve((size_t)NBC * ROWS * 4);
    unsigned* hist   = (unsigned*)carve((size_t)NBC * HB * 4 + (size_t)NBC * 4);  // hist + cnt contiguous
    unsigned* cnt    = hist + (size_t)NBC * HB;
    unsigned* pivot  = (unsigned*)carve((size_t)NBC * 4);
    int*      nselA  = (int*)     carve((size_t)NBC * 4);

    hipMemsetAsync(hist, 0, (size_t)NBC * HB * 4 + (size_t)NBC * 4, stream);
    hipMemsetAsync(out, 0, (size_t)out_size * 4, stream);

    int n1 = B * P;
    decode_kernel<<<(n1 + 255) / 256, 256, 0, stream>>>(loc, conf, prior, scores, cs, B, C, P);
    hist_kernel<<<dim3(NBC, HCHUNK), 256, 0, stream>>>(scores, cth, hist, P);
    pivot_kernel<<<NBC, 256, 0, stream>>>(hist, pivot);
    gather_kernel<<<dim3(NBC, 32), 256, 0, stream>>>(scores, pivot, cnt, cand, cth, P);
    sort_kernel<<<NBC, 1024, 0, stream>>>(cand, cnt, cs, rows, bx1, by1, bx2, by2, bar, nselA, P, Cfg);
    mask_kernel<<<dim3(NBC, ROWS / 64), 1024, 0, stream>>>(bx1, by1, bx2, by2, bar, nselA, nth, mask);
    reduce_pack_kernel<<<NBC, 64, 0, stream>>>(mask, nselA, rows, out);
}

// Round 9
// 245.590 us; speedup vs baseline: 1.0173x; 1.0173x over previous
//
#include <hip/hip_runtime.h>
#include <cstdint>
#include <cstddef>

typedef unsigned long long ull;

#define KTOP   1000
#define CAP    4096      // candidate gather capacity per (b,c)
#define HBITS  14
#define HB     (1 << HBITS)          // 16384 histogram bins (top-14 float bits)
#define HSHIFT (32 - HBITS)
#define ROWS   1024      // padded rank capacity (>= KTOP)
#define WORDS  16        // 1024 / 64 bitmask words per row
#define HCHUNK 16        // score chunks per (b,c) for the LDS histogram kernel

// ---------------- Kernel 1: softmax + SSD decode (pure streaming) ----------------
__global__ void decode_kernel(const float* __restrict__ loc,
                              const float* __restrict__ conf,
                              const float* __restrict__ prior,
                              float* __restrict__ scores,   // [B*Cfg][P]
                              float* __restrict__ cs,       // [B][P][4] center-size
                              int B, int C, int P) {
#pragma clang fp contract(off)
    int t = blockIdx.x * blockDim.x + threadIdx.x;
    if (t >= B * P) return;
    int b = t / P;
    int p = t - b * P;

    // softmax over class dim (C small)
    float x[8];
    float m = -INFINITY;
    for (int c = 0; c < C; ++c) {
        x[c] = conf[((size_t)b * C + c) * P + p];
        m = fmaxf(m, x[c]);
    }
    float sum = 0.f;
    for (int c = 0; c < C; ++c) {
        x[c] = expf(x[c] - m);
        sum += x[c];
    }
    for (int c = 1; c < C; ++c) {
        float v = x[c] / sum;
        int bc = b * (C - 1) + (c - 1);
        scores[(size_t)bc * P + p] = v;
    }

    // decode
    float l0 = loc[((size_t)b * 4 + 0) * P + p];
    float l1 = loc[((size_t)b * 4 + 1) * P + p];
    float l2 = loc[((size_t)b * 4 + 2) * P + p];
    float l3 = loc[((size_t)b * 4 + 3) * P + p];
    float pcx = prior[(size_t)p * 4 + 0];
    float pcy = prior[(size_t)p * 4 + 1];
    float pw  = prior[(size_t)p * 4 + 2];
    float ph  = prior[(size_t)p * 4 + 3];

    float cx = pcx + (l0 * 0.1f) * pw;
    float cy = pcy + (l1 * 0.1f) * ph;
    float w  = pw * expf(l2 * 0.2f);
    float h  = ph * expf(l3 * 0.2f);

    size_t o = ((size_t)b * P + p) * 4;
    cs[o + 0] = cx;
    cs[o + 1] = cy;
    cs[o + 2] = w;
    cs[o + 3] = h;
}

// ---------------- Kernel 1b: LDS-privatized score histogram ----------------
__global__ void __launch_bounds__(256)
hist_kernel(const float* __restrict__ scores,
            const float* __restrict__ cthp,
            unsigned* __restrict__ hist,     // [NBC][HB]
            int P) {
    __shared__ unsigned sh[HB / 2];          // 32 KB (16-bit packed counters)
    int bc  = blockIdx.x;
    int tid = threadIdx.x;
    float cth = *cthp;

    for (int i = tid; i < HB / 2; i += 256) sh[i] = 0u;
    __syncthreads();

    int chunk = (P + HCHUNK - 1) / HCHUNK;
    int lo = blockIdx.y * chunk;
    int hi = lo + chunk; if (hi > P) hi = P;
    const float* s = scores + (size_t)bc * P;
    for (int p = lo + tid; p < hi; p += 256) {
        float v = s[p];
        if (v >= cth) {
            unsigned bin = __float_as_uint(v) >> HSHIFT;
            atomicAdd(&sh[bin >> 1], (bin & 1u) ? 65536u : 1u);
        }
    }
    __syncthreads();

    unsigned* h = hist + (size_t)bc * HB;
    for (int i = tid; i < HB / 2; i += 256) {
        unsigned v = sh[i];
        if (v & 0xFFFFu)  atomicAdd(&h[2 * i],     v & 0xFFFFu);
        if (v >> 16)      atomicAdd(&h[2 * i + 1], v >> 16);
    }
}

// ---------------- Kernel 2: per-(b,c) pivot bin via parallel suffix scan ----------------
__global__ void __launch_bounds__(256)
pivot_kernel(const unsigned* __restrict__ hist, unsigned* __restrict__ pivot) {
    int bc  = blockIdx.x;
    int t   = threadIdx.x;
    const unsigned* h = hist + (size_t)bc * HB;
    __shared__ unsigned T[256];

    const int per = HB / 256;                // 64 bins per thread
    int base = t * per;
    unsigned S = 0;
    for (int i = 0; i < per; ++i) S += h[base + i];
    T[t] = S;
    __syncthreads();

    for (int d = 1; d < 256; d <<= 1) {
        unsigned add = (t + d < 256) ? T[t + d] : 0u;
        __syncthreads();
        T[t] += add;
        __syncthreads();
    }

    unsigned Tt = T[t];
    unsigned Tn = (t + 1 < 256) ? T[t + 1] : 0u;
    if (Tt >= (unsigned)KTOP && Tn < (unsigned)KTOP) {
        unsigned cum = Tn;
        for (int i = per - 1; i >= 0; --i) {
            cum += h[base + i];
            if (cum >= (unsigned)KTOP) { pivot[bc] = (unsigned)(base + i); break; }
        }
    }
    if (t == 0 && T[0] < (unsigned)KTOP) pivot[bc] = 0u;   // fewer than KTOP valid: take all
}

// ---------------- Kernel 3: gather with BLOCK-aggregated allocation ----------------
__global__ void __launch_bounds__(256)
gather_kernel(const float* __restrict__ scores,
              const unsigned* __restrict__ pivot,
              unsigned* __restrict__ cnt,
              ull* __restrict__ cand,
              const float* __restrict__ cthp, int P) {
    __shared__ unsigned wsum[4];
    __shared__ unsigned s_base;
    int bc = blockIdx.x;
    const float* s = scores + (size_t)bc * P;
    float cth = *cthp;
    unsigned pv = pivot[bc];
    int nchunk = gridDim.y;
    int chunk = (P + nchunk - 1) / nchunk;
    int lo = blockIdx.y * chunk;
    int hi = lo + chunk; if (hi > P) hi = P;
    int tid  = threadIdx.x;
    int lane = tid & 63;
    int wid  = tid >> 6;

    // phase 1: count
    unsigned mycnt = 0;
    for (int p = lo + tid; p < hi; p += 256) {
        float v = s[p];
        unsigned k = __float_as_uint(v);
        if (v >= cth && (k >> HSHIFT) >= pv) ++mycnt;
    }
    unsigned x = mycnt;
    for (int d = 1; d < 64; d <<= 1) {
        unsigned y = (unsigned)__shfl_up((int)x, d);
        if (lane >= d) x += y;
    }
    if (lane == 63) wsum[wid] = x;
    __syncthreads();
    if (tid == 0) {
        unsigned tot = 0;
        for (int w = 0; w < 4; ++w) { unsigned t2 = wsum[w]; wsum[w] = tot; tot += t2; }
        s_base = tot ? atomicAdd(&cnt[bc], tot) : 0u;
    }
    __syncthreads();
    unsigned off = s_base + wsum[wid] + (x - mycnt);

    // phase 2: write (chunk is L2-hot from phase 1)
    ull* cb = cand + (size_t)bc * CAP;
    for (int p = lo + tid; p < hi; p += 256) {
        float v = s[p];
        unsigned k = __float_as_uint(v);
        if (v >= cth && (k >> HSHIFT) >= pv) {
            if (off < CAP)
                cb[off] = ((ull)k << 32) | (unsigned)(~(unsigned)p);
            ++off;
        }
    }
}

// ---------------- Kernel 4: per-(b,c) bitonic sort + export sorted boxes ----------------
__global__ void __launch_bounds__(1024)
sort_kernel(const ull* __restrict__ cand,
            const unsigned* __restrict__ cnt,
            const float* __restrict__ cs,
            float* __restrict__ rows,      // [NBC][KTOP][5] score,cx,cy,w,h
            float* __restrict__ bx1, float* __restrict__ by1,
            float* __restrict__ bx2, float* __restrict__ by2,
            float* __restrict__ bar,       // SoA [NBC][ROWS]
            int* __restrict__ nselArr,
            int P, int Cfg) {
#pragma clang fp contract(off)
    int bc  = blockIdx.x;
    int b   = bc / Cfg;
    int tid = threadIdx.x;
    __shared__ ull sbuf[CAP];

    int M = (int)cnt[bc]; if (M > CAP) M = CAP;
    int nsel = M < KTOP ? M : KTOP;
    if (tid == 0) nselArr[bc] = nsel;

    int n = 1024;
    while (n < M) n <<= 1;
    for (int i = tid; i < n; i += 1024)
        sbuf[i] = (i < M) ? cand[(size_t)bc * CAP + i] : 0ull;
    __syncthreads();

    for (unsigned k = 2; k <= (unsigned)n; k <<= 1) {
        for (unsigned j = k >> 1; j > 0; j >>= 1) {
            for (unsigned i = tid; i < (unsigned)n; i += 1024) {
                unsigned ixj = i ^ j;
                if (ixj > i) {
                    bool up = ((i & k) == 0u);
                    ull a = sbuf[i], bb = sbuf[ixj];
                    if ((a > bb) == up) { sbuf[i] = bb; sbuf[ixj] = a; }
                }
            }
            __syncthreads();
        }
    }

    for (int r = tid; r < nsel; r += 1024) {
        ull e = sbuf[n - 1 - r];
        float sc = __uint_as_float((unsigned)(e >> 32));
        int idx = (int)(~(unsigned)e);
        const float* c4 = cs + ((size_t)b * P + idx) * 4;
        float cx = c4[0], cy = c4[1], w = c4[2], h = c4[3];
        float x1 = cx - w / 2.f, y1 = cy - h / 2.f;
        float x2 = cx + w / 2.f, y2 = cy + h / 2.f;
        size_t sb = (size_t)bc * ROWS + r;
        bx1[sb] = x1; by1[sb] = y1; bx2[sb] = x2; by2[sb] = y2;
        bar[sb] = fmaxf(x2 - x1, 0.f) * fmaxf(y2 - y1, 0.f);
        float* rr = rows + ((size_t)bc * KTOP + r) * 5;
        rr[0] = sc; rr[1] = cx; rr[2] = cy; rr[3] = w; rr[4] = h;
    }
}

// ---------------- Kernel 5: GPU-wide suppression bitmask matrix ----------------
__global__ void __launch_bounds__(1024)
mask_kernel(const float* __restrict__ bx1, const float* __restrict__ by1,
            const float* __restrict__ bx2, const float* __restrict__ by2,
            const float* __restrict__ bar,
            const int* __restrict__ nselArr,
            const float* __restrict__ nthp,
            ull* __restrict__ mask) {       // [NBC][ROWS][WORDS]
#pragma clang fp contract(off)
    int bc   = blockIdx.x;
    int tile = blockIdx.y;                  // 16 tiles x 64 rows
    int tid  = threadIdx.x;
    int nsel = nselArr[bc];
    float nth = *nthp;

    __shared__ float sx1[ROWS], sy1[ROWS], sx2[ROWS], sy2[ROWS], sar[ROWS];
    size_t sb = (size_t)bc * ROWS;
    if (tid < nsel) {
        sx1[tid] = bx1[sb + tid]; sy1[tid] = by1[sb + tid];
        sx2[tid] = bx2[sb + tid]; sy2[tid] = by2[sb + tid];
        sar[tid] = bar[sb + tid];
    }
    __syncthreads();

    int i = tile * 64 + (tid >> 4);
    int w = tid & 15;
    if (i >= nsel) return;

    float xi1 = sx1[i], yi1 = sy1[i], xi2 = sx2[i], yi2 = sy2[i], ai = sar[i];
    ull bits = 0ull;
    int j0 = w << 6;
    for (int jj0 = 0; jj0 < 64; ++jj0) {
        int jj = (jj0 + (w << 2)) & 63;
        int j = j0 + jj;
        if (j > i && j < nsel) {
            float ww = fmaxf(fminf(xi2, sx2[j]) - fmaxf(xi1, sx1[j]), 0.f);
            float hh = fmaxf(fminf(yi2, sy2[j]) - fmaxf(yi1, sy1[j]), 0.f);
            float inter = ww * hh;
            float uni = ai + sar[j] - inter;
            float iou = inter / fmaxf(uni, 1e-12f);
            if (iou > nth) bits |= 1ull << jj;
        }
    }
    mask[(((size_t)bc * ROWS + i) << 4) + w] = bits;
}

// ---------------- Kernel 6: serial bit-OR reduction, register-fed chain ----------------
// One wave per (b,c). The chunk's 64 diagonal words live wave-distributed:
// lane i holds row i's word c (ONE ds_read per chunk, off-chain). The serial
// loop is fed by __shfl with compile-time lane indices (v_readlane/bpermute,
// no LDS round-trip), software-pipelined 8 ranks ahead. Chain per rank =
// 3 VALU ops via sign-extend mask. kept = ~cur_final (suppression bits for
// rank j are only ever set by ranks i<j, all processed before j's decision).
__global__ void __launch_bounds__(64)
reduce_pack_kernel(const ull* __restrict__ mask,
                   const int* __restrict__ nselArr,
                   const float* __restrict__ rows,
                   float* __restrict__ out) {
    int bc   = blockIdx.x;
    int lane = threadIdx.x;                 // 64 threads = 1 wave
    int nsel = nselArr[bc];
    const ull* mrow = mask + ((size_t)bc * ROWS << 4);

    __shared__ ull sm[2048];                // 2 x (64 rows x 16 words) = 16 KB

    int nchunk = (nsel + 63) >> 6;          // <= 16
    ull S = 0ull;                           // lane w<16 holds suppressed-word w
    int g = lane >> 4;                      // row-group 0..3 for bulk apply
    int w = lane & 15;                      // word index for bulk apply
    int rsub = lane >> 4;                   // sub-row within a k-load (4 rows/k)

    if (nchunk > 0) {
        ull r[16];
        // preload chunk 0, zero-padding rows >= nsel
        #pragma unroll
        for (int k = 0; k < 16; ++k) {
            int row = (k << 2) + rsub;
            ull v = mrow[k * 64 + lane];
            r[k] = (row < nsel) ? v : 0ull;
        }
        #pragma unroll
        for (int k = 0; k < 16; ++k) sm[k * 64 + lane] = r[k];

        for (int c = 0; c < nchunk; ++c) {
            int cb = (c & 1) << 10;
            int nb = ((c + 1) & 1) << 10;
            bool more = (c + 1) < nchunk;
            if (more) {                      // issue next chunk's global loads
                #pragma unroll
                for (int k = 0; k < 16; ++k) {
                    int row = ((c + 1) << 6) + (k << 2) + rsub;
                    ull v = mrow[(size_t)(c + 1) * 1024 + k * 64 + lane];
                    r[k] = (row < nsel) ? v : 0ull;
                }
            }

            // lane i <- row i's word c (single LDS instruction, off-chain)
            ull dreg = sm[cb + (lane << 4) + c];
            ull cur  = __shfl(S, c);

            // ---- serial greedy, register-fed + software-pipelined 8x8 ----
            ull dbuf[8], dnext[8];
            #pragma unroll
            for (int k = 0; k < 8; ++k) dbuf[k] = __shfl(dreg, k);
            #pragma unroll
            for (int grp = 0; grp < 8; ++grp) {
                if (grp < 7) {
                    #pragma unroll
                    for (int k = 0; k < 8; ++k)
                        dnext[k] = __shfl(dreg, (grp + 1) * 8 + k);
                }
                #pragma unroll
                for (int k = 0; k < 8; ++k) {
                    int i = grp * 8 + k;
                    // all-ones iff rank i suppressed (bit i of cur)
                    ull supm = (ull)((long long)(cur << (63 - i)) >> 63);
                    cur |= dbuf[k] & ~supm;
                }
                if (grp < 7) {
                    #pragma unroll
                    for (int k = 0; k < 8; ++k) dbuf[k] = dnext[k];
                }
            }
            ull kbits = ~cur;                // kept = not suppressed

            // ---- bulk apply: lane (g,w) ORs kept rows of group g, word w ----
            unsigned sub = (unsigned)((kbits >> (g << 4)) & 0xFFFFull);
            int rbase2 = cb + (g << 8) + w;
            ull part = 0ull;
            #pragma unroll
            for (int i = 0; i < 16; ++i) {
                ull v = sm[rbase2 + (i << 4)];   // unconditional, pipelined
                part |= v & (ull)(0ll - (long long)((sub >> i) & 1u));
            }
            part |= __shfl_xor(part, 16);
            part |= __shfl_xor(part, 32);
            S |= part;                           // lanes 0..15 meaningful
            if (lane == c) S = cur;              // finalize word c

            if (more) {
                #pragma unroll
                for (int k = 0; k < 16; ++k) sm[nb + k * 64 + lane] = r[k];
            }
        }
    }

    // ---- kept bitmap -> compact positions -> write packed rows ----
    int base_i = lane << 6;
    ull valid = 0ull;
    if (lane < WORDS) {
        int rem = nsel - base_i;
        if (rem > 0) valid = (rem >= 64) ? ~0ull : ((1ull << rem) - 1ull);
    }
    ull K = (~S) & valid;
    int cpc = __popcll(K);
    int x = cpc;
    for (int d = 1; d < 64; d <<= 1) {
        int y = __shfl_up(x, d);
        if (lane >= d) x += y;
    }
    int pos = x - cpc;

    const float* rbase = rows + (size_t)bc * KTOP * 5;
    float* obase = out + (size_t)bc * KTOP * 5;
    for (int bit = 0; bit < 64; ++bit) {
        if ((K >> bit) & 1ull) {
            int i = base_i + bit;
            const float* rr = rbase + i * 5;
            float* oo = obase + pos * 5;
            oo[0] = rr[0]; oo[1] = rr[1]; oo[2] = rr[2]; oo[3] = rr[3]; oo[4] = rr[4];
            ++pos;
        }
    }
}

// ------------------------------- launcher -------------------------------
extern "C" void kernel_launch(void* const* d_in, const int* in_sizes, int n_in,
                              void* d_out, int out_size, void* d_ws, size_t ws_size,
                              hipStream_t stream) {
    (void)n_in; (void)ws_size;
    const float* loc   = (const float*)d_in[0];
    const float* conf  = (const float*)d_in[1];
    const float* prior = (const float*)d_in[2];
    const float* cth   = (const float*)d_in[3];
    const float* nth   = (const float*)d_in[4];
    float* out = (float*)d_out;

    int P   = in_sizes[2] / 4;
    int B   = in_sizes[0] / (4 * P);
    int C   = in_sizes[1] / (B * P);
    int Cfg = C - 1;
    int NBC = B * Cfg;

    // ---- carve workspace (256B aligned sections; 8B types first) ----
    char* base = (char*)d_ws;
    size_t off = 0;
    auto carve = [&](size_t bytes) { char* p = base + off; off = (off + bytes + 255) & ~(size_t)255; return p; };

    ull*      cand   = (ull*)     carve((size_t)NBC * CAP * 8);
    ull*      mask   = (ull*)     carve((size_t)NBC * ROWS * WORDS * 8);
    float*    scores = (float*)   carve((size_t)NBC * P * 4);
    float*    cs     = (float*)   carve((size_t)B * P * 4 * 4);
    float*    rows   = (float*)   carve((size_t)NBC * KTOP * 5 * 4);
    float*    bx1    = (float*)   carve((size_t)NBC * ROWS * 4);
    float*    by1    = (float*)   carve((size_t)NBC * ROWS * 4);
    float*    bx2    = (float*)   carve((size_t)NBC * ROWS * 4);
    float*    by2    = (float*)   carve((size_t)NBC * ROWS * 4);
    float*    bar    = (float*)   carve((size_t)NBC * ROWS * 4);
    unsigned* hist   = (unsigned*)carve((size_t)NBC * HB * 4 + (size_t)NBC * 4);  // hist + cnt contiguous
    unsigned* cnt    = hist + (size_t)NBC * HB;
    unsigned* pivot  = (unsigned*)carve((size_t)NBC * 4);
    int*      nselA  = (int*)     carve((size_t)NBC * 4);

    hipMemsetAsync(hist, 0, (size_t)NBC * HB * 4 + (size_t)NBC * 4, stream);
    hipMemsetAsync(out, 0, (size_t)out_size * 4, stream);

    int n1 = B * P;
    decode_kernel<<<(n1 + 255) / 256, 256, 0, stream>>>(loc, conf, prior, scores, cs, B, C, P);
    hist_kernel<<<dim3(NBC, HCHUNK), 256, 0, stream>>>(scores, cth, hist, P);
    pivot_kernel<<<NBC, 256, 0, stream>>>(hist, pivot);
    gather_kernel<<<dim3(NBC, 32), 256, 0, stream>>>(scores, pivot, cnt, cand, cth, P);
    sort_kernel<<<NBC, 1024, 0, stream>>>(cand, cnt, cs, rows, bx1, by1, bx2, by2, bar, nselA, P, Cfg);
    mask_kernel<<<dim3(NBC, ROWS / 64), 1024, 0, stream>>>(bx1, by1, bx2, by2, bar, nselA, nth, mask);
    reduce_pack_kernel<<<NBC, 64, 0, stream>>>(mask, nselA, rows, out);
}

// Round 10
// 230.877 us; speedup vs baseline: 1.0821x; 1.0637x over previous
//
#include <hip/hip_runtime.h>
#include <cstdint>
#include <cstddef>

typedef unsigned long long ull;

#define KTOP   1000
#define CAP    4096      // candidate gather capacity per (b,c)
#define HBITS  14
#define HB     (1 << HBITS)          // 16384 histogram bins (top-14 float bits)
#define HSHIFT (32 - HBITS)
#define ROWS   1024      // padded rank capacity (>= KTOP)
#define WORDS  16        // 1024 / 64 bitmask words per row
#define HCHUNK 16        // score chunks per (b,c) for the LDS histogram kernel

// ---------------- Kernel 1: softmax + SSD decode (pure streaming) ----------------
__global__ void decode_kernel(const float* __restrict__ loc,
                              const float* __restrict__ conf,
                              const float* __restrict__ prior,
                              float* __restrict__ scores,   // [B*Cfg][P]
                              float* __restrict__ cs,       // [B][P][4] center-size
                              int B, int C, int P) {
#pragma clang fp contract(off)
    int t = blockIdx.x * blockDim.x + threadIdx.x;
    if (t >= B * P) return;
    int b = t / P;
    int p = t - b * P;

    // softmax over class dim (C small)
    float x[8];
    float m = -INFINITY;
    for (int c = 0; c < C; ++c) {
        x[c] = conf[((size_t)b * C + c) * P + p];
        m = fmaxf(m, x[c]);
    }
    float sum = 0.f;
    for (int c = 0; c < C; ++c) {
        x[c] = expf(x[c] - m);
        sum += x[c];
    }
    for (int c = 1; c < C; ++c) {
        float v = x[c] / sum;
        int bc = b * (C - 1) + (c - 1);
        scores[(size_t)bc * P + p] = v;
    }

    // decode
    float l0 = loc[((size_t)b * 4 + 0) * P + p];
    float l1 = loc[((size_t)b * 4 + 1) * P + p];
    float l2 = loc[((size_t)b * 4 + 2) * P + p];
    float l3 = loc[((size_t)b * 4 + 3) * P + p];
    float pcx = prior[(size_t)p * 4 + 0];
    float pcy = prior[(size_t)p * 4 + 1];
    float pw  = prior[(size_t)p * 4 + 2];
    float ph  = prior[(size_t)p * 4 + 3];

    float cx = pcx + (l0 * 0.1f) * pw;
    float cy = pcy + (l1 * 0.1f) * ph;
    float w  = pw * expf(l2 * 0.2f);
    float h  = ph * expf(l3 * 0.2f);

    size_t o = ((size_t)b * P + p) * 4;
    cs[o + 0] = cx;
    cs[o + 1] = cy;
    cs[o + 2] = w;
    cs[o + 3] = h;
}

// ---------------- Kernel 1b: LDS-privatized score histogram ----------------
__global__ void __launch_bounds__(256)
hist_kernel(const float* __restrict__ scores,
            const float* __restrict__ cthp,
            unsigned* __restrict__ hist,     // [NBC][HB]
            int P) {
    __shared__ unsigned sh[HB / 2];          // 32 KB (16-bit packed counters)
    int bc  = blockIdx.x;
    int tid = threadIdx.x;
    float cth = *cthp;

    for (int i = tid; i < HB / 2; i += 256) sh[i] = 0u;
    __syncthreads();

    int chunk = (P + HCHUNK - 1) / HCHUNK;
    int lo = blockIdx.y * chunk;
    int hi = lo + chunk; if (hi > P) hi = P;
    const float* s = scores + (size_t)bc * P;
    for (int p = lo + tid; p < hi; p += 256) {
        float v = s[p];
        if (v >= cth) {
            unsigned bin = __float_as_uint(v) >> HSHIFT;
            atomicAdd(&sh[bin >> 1], (bin & 1u) ? 65536u : 1u);
        }
    }
    __syncthreads();

    unsigned* h = hist + (size_t)bc * HB;
    for (int i = tid; i < HB / 2; i += 256) {
        unsigned v = sh[i];
        if (v & 0xFFFFu)  atomicAdd(&h[2 * i],     v & 0xFFFFu);
        if (v >> 16)      atomicAdd(&h[2 * i + 1], v >> 16);
    }
}

// ---------------- Kernel 2: per-(b,c) pivot bin via parallel suffix scan ----------------
__global__ void __launch_bounds__(256)
pivot_kernel(const unsigned* __restrict__ hist, unsigned* __restrict__ pivot) {
    int bc  = blockIdx.x;
    int t   = threadIdx.x;
    const unsigned* h = hist + (size_t)bc * HB;
    __shared__ unsigned T[256];

    const int per = HB / 256;                // 64 bins per thread
    int base = t * per;
    unsigned S = 0;
    for (int i = 0; i < per; ++i) S += h[base + i];
    T[t] = S;
    __syncthreads();

    for (int d = 1; d < 256; d <<= 1) {
        unsigned add = (t + d < 256) ? T[t + d] : 0u;
        __syncthreads();
        T[t] += add;
        __syncthreads();
    }

    unsigned Tt = T[t];
    unsigned Tn = (t + 1 < 256) ? T[t + 1] : 0u;
    if (Tt >= (unsigned)KTOP && Tn < (unsigned)KTOP) {
        unsigned cum = Tn;
        for (int i = per - 1; i >= 0; --i) {
            cum += h[base + i];
            if (cum >= (unsigned)KTOP) { pivot[bc] = (unsigned)(base + i); break; }
        }
    }
    if (t == 0 && T[0] < (unsigned)KTOP) pivot[bc] = 0u;   // fewer than KTOP valid: take all
}

// ---------------- Kernel 3: gather with BLOCK-aggregated allocation ----------------
__global__ void __launch_bounds__(256)
gather_kernel(const float* __restrict__ scores,
              const unsigned* __restrict__ pivot,
              unsigned* __restrict__ cnt,
              ull* __restrict__ cand,
              const float* __restrict__ cthp, int P) {
    __shared__ unsigned wsum[4];
    __shared__ unsigned s_base;
    int bc = blockIdx.x;
    const float* s = scores + (size_t)bc * P;
    float cth = *cthp;
    unsigned pv = pivot[bc];
    int nchunk = gridDim.y;
    int chunk = (P + nchunk - 1) / nchunk;
    int lo = blockIdx.y * chunk;
    int hi = lo + chunk; if (hi > P) hi = P;
    int tid  = threadIdx.x;
    int lane = tid & 63;
    int wid  = tid >> 6;

    // phase 1: count
    unsigned mycnt = 0;
    for (int p = lo + tid; p < hi; p += 256) {
        float v = s[p];
        unsigned k = __float_as_uint(v);
        if (v >= cth && (k >> HSHIFT) >= pv) ++mycnt;
    }
    unsigned x = mycnt;
    for (int d = 1; d < 64; d <<= 1) {
        unsigned y = (unsigned)__shfl_up((int)x, d);
        if (lane >= d) x += y;
    }
    if (lane == 63) wsum[wid] = x;
    __syncthreads();
    if (tid == 0) {
        unsigned tot = 0;
        for (int w = 0; w < 4; ++w) { unsigned t2 = wsum[w]; wsum[w] = tot; tot += t2; }
        s_base = tot ? atomicAdd(&cnt[bc], tot) : 0u;
    }
    __syncthreads();
    unsigned off = s_base + wsum[wid] + (x - mycnt);

    // phase 2: write (chunk is L2-hot from phase 1)
    ull* cb = cand + (size_t)bc * CAP;
    for (int p = lo + tid; p < hi; p += 256) {
        float v = s[p];
        unsigned k = __float_as_uint(v);
        if (v >= cth && (k >> HSHIFT) >= pv) {
            if (off < CAP)
                cb[off] = ((ull)k << 32) | (unsigned)(~(unsigned)p);
            ++off;
        }
    }
}

// ---------------- Kernel 4: per-(b,c) bitonic sort + export sorted boxes ----------------
__global__ void __launch_bounds__(1024)
sort_kernel(const ull* __restrict__ cand,
            const unsigned* __restrict__ cnt,
            const float* __restrict__ cs,
            float* __restrict__ rows,      // [NBC][KTOP][5] score,cx,cy,w,h
            float* __restrict__ bx1, float* __restrict__ by1,
            float* __restrict__ bx2, float* __restrict__ by2,
            float* __restrict__ bar,       // SoA [NBC][ROWS]
            int* __restrict__ nselArr,
            int P, int Cfg) {
#pragma clang fp contract(off)
    int bc  = blockIdx.x;
    int b   = bc / Cfg;
    int tid = threadIdx.x;
    __shared__ ull sbuf[CAP];

    int M = (int)cnt[bc]; if (M > CAP) M = CAP;
    int nsel = M < KTOP ? M : KTOP;
    if (tid == 0) nselArr[bc] = nsel;

    int n = 1024;
    while (n < M) n <<= 1;
    for (int i = tid; i < n; i += 1024)
        sbuf[i] = (i < M) ? cand[(size_t)bc * CAP + i] : 0ull;
    __syncthreads();

    for (unsigned k = 2; k <= (unsigned)n; k <<= 1) {
        for (unsigned j = k >> 1; j > 0; j >>= 1) {
            for (unsigned i = tid; i < (unsigned)n; i += 1024) {
                unsigned ixj = i ^ j;
                if (ixj > i) {
                    bool up = ((i & k) == 0u);
                    ull a = sbuf[i], bb = sbuf[ixj];
                    if ((a > bb) == up) { sbuf[i] = bb; sbuf[ixj] = a; }
                }
            }
            __syncthreads();
        }
    }

    for (int r = tid; r < nsel; r += 1024) {
        ull e = sbuf[n - 1 - r];
        float sc = __uint_as_float((unsigned)(e >> 32));
        int idx = (int)(~(unsigned)e);
        const float* c4 = cs + ((size_t)b * P + idx) * 4;
        float cx = c4[0], cy = c4[1], w = c4[2], h = c4[3];
        float x1 = cx - w / 2.f, y1 = cy - h / 2.f;
        float x2 = cx + w / 2.f, y2 = cy + h / 2.f;
        size_t sb = (size_t)bc * ROWS + r;
        bx1[sb] = x1; by1[sb] = y1; bx2[sb] = x2; by2[sb] = y2;
        bar[sb] = fmaxf(x2 - x1, 0.f) * fmaxf(y2 - y1, 0.f);
        float* rr = rows + ((size_t)bc * KTOP + r) * 5;
        rr[0] = sc; rr[1] = cx; rr[2] = cy; rr[3] = w; rr[4] = h;
    }
}

// ---------------- Kernel 5: GPU-wide suppression bitmask matrix ----------------
// Rows >= nsel are ZERO-FILLED (not skipped): downstream consumes the full
// 1024-row tile with no padding logic.
__global__ void __launch_bounds__(1024)
mask_kernel(const float* __restrict__ bx1, const float* __restrict__ by1,
            const float* __restrict__ bx2, const float* __restrict__ by2,
            const float* __restrict__ bar,
            const int* __restrict__ nselArr,
            const float* __restrict__ nthp,
            ull* __restrict__ mask) {       // [NBC][ROWS][WORDS]
#pragma clang fp contract(off)
    int bc   = blockIdx.x;
    int tile = blockIdx.y;                  // 16 tiles x 64 rows
    int tid  = threadIdx.x;
    int nsel = nselArr[bc];
    float nth = *nthp;

    __shared__ float sx1[ROWS], sy1[ROWS], sx2[ROWS], sy2[ROWS], sar[ROWS];
    size_t sb = (size_t)bc * ROWS;
    if (tid < nsel) {
        sx1[tid] = bx1[sb + tid]; sy1[tid] = by1[sb + tid];
        sx2[tid] = bx2[sb + tid]; sy2[tid] = by2[sb + tid];
        sar[tid] = bar[sb + tid];
    }
    __syncthreads();

    int i = tile * 64 + (tid >> 4);
    int w = tid & 15;
    if (i >= nsel) {
        mask[(((size_t)bc * ROWS + i) << 4) + w] = 0ull;   // zero-fill padding rows
        return;
    }

    float xi1 = sx1[i], yi1 = sy1[i], xi2 = sx2[i], yi2 = sy2[i], ai = sar[i];
    ull bits = 0ull;
    int j0 = w << 6;
    for (int jj0 = 0; jj0 < 64; ++jj0) {
        int jj = (jj0 + (w << 2)) & 63;
        int j = j0 + jj;
        if (j > i && j < nsel) {
            float ww = fmaxf(fminf(xi2, sx2[j]) - fmaxf(xi1, sx1[j]), 0.f);
            float hh = fmaxf(fminf(yi2, sy2[j]) - fmaxf(yi1, sy1[j]), 0.f);
            float inter = ww * hh;
            float uni = ai + sar[j] - inter;
            float iou = inter / fmaxf(uni, 1e-12f);
            if (iou > nth) bits |= 1ull << jj;
        }
    }
    mask[(((size_t)bc * ROWS + i) << 4) + w] = bits;
}

// ---------------- Kernel 6a: serial bit-OR reduction -> kept bitmap ----------------
// One wave per (b,c). Depth-2 register prefetch (compile-time double-buffered
// via unroll-by-2 + inline body): chunk c+2's loads are issued while chunk c
// computes, giving each load ~2 body-lengths in flight. Serial feed = LDS
// broadcast reads (uniform address, conflict-free), fully unrolled. Writes
// only the 16-word kept bitmap; packing is a separate parallel kernel.
__device__ __forceinline__ void nms_chunk_body(
    int c, int nchunk, int lane, int g, int w,
    const ull* __restrict__ mrow, ull* sm,
    ull (&pr)[16], ull (&st)[16], ull& S)
{
    int cb = (c & 1) << 10;
    int nb = ((c + 1) & 1) << 10;
    if (c + 2 < nchunk) {                    // prefetch chunk c+2 (regs free: chunk c already staged)
        #pragma unroll
        for (int k = 0; k < 16; ++k)
            pr[k] = mrow[(size_t)(c + 2) * 1024 + k * 64 + lane];
    }

    // ---- serial greedy on word c (all lanes redundant; broadcast LDS reads) ----
    ull cur = __shfl(S, c);
    #pragma unroll
    for (int i = 0; i < 64; ++i) {
        ull di   = sm[cb + (i << 4) + c];
        ull supm = (ull)((long long)(cur << (63 - i)) >> 63);  // all-ones iff rank i suppressed
        cur |= di & ~supm;
    }
    ull kbits = ~cur;                        // kept = not suppressed

    // ---- bulk apply: lane (g,w) ORs kept rows of group g, word w ----
    unsigned sub = (unsigned)((kbits >> (g << 4)) & 0xFFFFull);
    int rbase2 = cb + (g << 8) + w;
    ull part = 0ull;
    #pragma unroll
    for (int i = 0; i < 16; ++i) {
        ull v = sm[rbase2 + (i << 4)];       // unconditional, pipelined
        part |= v & (ull)(0ll - (long long)((sub >> i) & 1u));
    }
    part |= __shfl_xor(part, 16);
    part |= __shfl_xor(part, 32);
    S |= part;                               // lanes 0..15 meaningful
    if (lane == c) S = cur;                  // finalize word c

    if (c + 1 < nchunk) {                    // stage chunk c+1 into the other LDS buffer
        #pragma unroll
        for (int k = 0; k < 16; ++k) sm[nb + k * 64 + lane] = st[k];
    }
}

__global__ void __launch_bounds__(64)
nms_reduce_kernel(const ull* __restrict__ mask,
                  const int* __restrict__ nselArr,
                  ull* __restrict__ keepW) {       // [NBC][16]
    int bc   = blockIdx.x;
    int lane = threadIdx.x;                 // 64 threads = 1 wave
    int nsel = nselArr[bc];
    const ull* mrow = mask + ((size_t)bc * ROWS << 4);

    __shared__ ull sm[2048];                // 2 x (64 rows x 16 words) = 16 KB

    int nchunk = (nsel + 63) >> 6;          // <= 16
    ull S = 0ull;                           // lane w<16 holds suppressed-word w
    int g = lane >> 4;
    int w = lane & 15;

    ull ra[16], rb[16];
    if (nchunk > 0) {
        #pragma unroll
        for (int k = 0; k < 16; ++k) ra[k] = mrow[k * 64 + lane];              // chunk 0
        if (nchunk > 1) {
            #pragma unroll
            for (int k = 0; k < 16; ++k) rb[k] = mrow[1024 + k * 64 + lane];   // chunk 1
        }
        #pragma unroll
        for (int k = 0; k < 16; ++k) sm[k * 64 + lane] = ra[k];                // stage chunk 0

        #pragma unroll 1
        for (int cc = 0; cc < 8; ++cc) {
            int c0 = cc << 1;
            if (c0 >= nchunk) break;
            nms_chunk_body(c0, nchunk, lane, g, w, mrow, sm, ra, rb, S);
            int c1 = c0 + 1;
            if (c1 >= nchunk) break;
            nms_chunk_body(c1, nchunk, lane, g, w, mrow, sm, rb, ra, S);
        }
    }

    // ---- store kept bitmap (valid-masked) ----
    if (lane < WORDS) {
        int base_i = lane << 6;
        ull valid = 0ull;
        int rem = nsel - base_i;
        if (rem > 0) valid = (rem >= 64) ? ~0ull : ((1ull << rem) - 1ull);
        keepW[(size_t)bc * WORDS + lane] = (~S) & valid;
    }
}

// ---------------- Kernel 6b: parallel compaction + write ----------------
__global__ void __launch_bounds__(256)
pack_kernel(const ull* __restrict__ keepW,
            const float* __restrict__ rows,
            float* __restrict__ out) {
    int bc  = blockIdx.x;
    int tid = threadIdx.x;
    __shared__ ull kw[WORDS];
    __shared__ unsigned pref[WORDS];

    if (tid < WORDS) kw[tid] = keepW[(size_t)bc * WORDS + tid];
    __syncthreads();
    if (tid == 0) {
        unsigned c = 0;
        for (int w = 0; w < WORDS; ++w) { pref[w] = c; c += (unsigned)__popcll(kw[w]); }
    }
    __syncthreads();

    const float* rbase = rows + (size_t)bc * KTOP * 5;
    float* obase = out + (size_t)bc * KTOP * 5;
    for (int r = tid; r < KTOP; r += 256) {
        ull wv = kw[r >> 6];
        if ((wv >> (r & 63)) & 1ull) {
            int pos = (int)pref[r >> 6] + __popcll(wv & ((1ull << (r & 63)) - 1ull));
            const float* rr = rbase + r * 5;
            float* oo = obase + pos * 5;
            oo[0] = rr[0]; oo[1] = rr[1]; oo[2] = rr[2]; oo[3] = rr[3]; oo[4] = rr[4];
        }
    }
}

// ------------------------------- launcher -------------------------------
extern "C" void kernel_launch(void* const* d_in, const int* in_sizes, int n_in,
                              void* d_out, int out_size, void* d_ws, size_t ws_size,
                              hipStream_t stream) {
    (void)n_in; (void)ws_size;
    const float* loc   = (const float*)d_in[0];
    const float* conf  = (const float*)d_in[1];
    const float* prior = (const float*)d_in[2];
    const float* cth   = (const float*)d_in[3];
    const float* nth   = (const float*)d_in[4];
    float* out = (float*)d_out;

    int P   = in_sizes[2] / 4;
    int B   = in_sizes[0] / (4 * P);
    int C   = in_sizes[1] / (B * P);
    int Cfg = C - 1;
    int NBC = B * Cfg;

    // ---- carve workspace (256B aligned sections; 8B types first) ----
    char* base = (char*)d_ws;
    size_t off = 0;
    auto carve = [&](size_t bytes) { char* p = base + off; off = (off + bytes + 255) & ~(size_t)255; return p; };

    ull*      cand   = (ull*)     carve((size_t)NBC * CAP * 8);
    ull*      mask   = (ull*)     carve((size_t)NBC * ROWS * WORDS * 8);
    ull*      keepW  = (ull*)     carve((size_t)NBC * WORDS * 8);
    float*    scores = (float*)   carve((size_t)NBC * P * 4);
    float*    cs     = (float*)   carve((size_t)B * P * 4 * 4);
    float*    rows   = (float*)   carve((size_t)NBC * KTOP * 5 * 4);
    float*    bx1    = (float*)   carve((size_t)NBC * ROWS * 4);
    float*    by1    = (float*)   carve((size_t)NBC * ROWS * 4);
    float*    bx2    = (float*)   carve((size_t)NBC * ROWS * 4);
    float*    by2    = (float*)   carve((size_t)NBC * ROWS * 4);
    float*    bar    = (float*)   carve((size_t)NBC * ROWS * 4);
    unsigned* hist   = (unsigned*)carve((size_t)NBC * HB * 4 + (size_t)NBC * 4);  // hist + cnt contiguous
    unsigned* cnt    = hist + (size_t)NBC * HB;
    unsigned* pivot  = (unsigned*)carve((size_t)NBC * 4);
    int*      nselA  = (int*)     carve((size_t)NBC * 4);

    hipMemsetAsync(hist, 0, (size_t)NBC * HB * 4 + (size_t)NBC * 4, stream);
    hipMemsetAsync(out, 0, (size_t)out_size * 4, stream);

    int n1 = B * P;
    decode_kernel<<<(n1 + 255) / 256, 256, 0, stream>>>(loc, conf, prior, scores, cs, B, C, P);
    hist_kernel<<<dim3(NBC, HCHUNK), 256, 0, stream>>>(scores, cth, hist, P);
    pivot_kernel<<<NBC, 256, 0, stream>>>(hist, pivot);
    gather_kernel<<<dim3(NBC, 32), 256, 0, stream>>>(scores, pivot, cnt, cand, cth, P);
    sort_kernel<<<NBC, 1024, 0, stream>>>(cand, cnt, cs, rows, bx1, by1, bx2, by2, bar, nselA, P, Cfg);
    mask_kernel<<<dim3(NBC, ROWS / 64), 1024, 0, stream>>>(bx1, by1, bx2, by2, bar, nselA, nth, mask);
    nms_reduce_kernel<<<NBC, 64, 0, stream>>>(mask, nselA, keepW);
    pack_kernel<<<NBC, 256, 0, stream>>>(keepW, rows, out);
}

// Round 11
// 225.591 us; speedup vs baseline: 1.1075x; 1.0234x over previous
//
#include <hip/hip_runtime.h>
#include <cstdint>
#include <cstddef>

typedef unsigned long long ull;

#define KTOP   1000
#define CAP    4096      // candidate gather capacity per (b,c)
#define HBITS  14
#define HB     (1 << HBITS)          // 16384 histogram bins (top-14 float bits)
#define HSHIFT (32 - HBITS)
#define ROWS   1024      // padded rank capacity (>= KTOP)
#define WORDS  16        // 1024 / 64 bitmask words per row
#define HCHUNK 16        // score chunks per (b,c) for the LDS histogram kernel

// ---------------- Kernel 1: softmax + SSD decode + hist zeroing ----------------
__global__ void decode_kernel(const float* __restrict__ loc,
                              const float* __restrict__ conf,
                              const float* __restrict__ prior,
                              float* __restrict__ scores,   // [B*Cfg][P]
                              float* __restrict__ cs,       // [B][P][4] center-size
                              unsigned* __restrict__ histz, // hist+cnt region to zero
                              int histW,
                              int B, int C, int P) {
#pragma clang fp contract(off)
    int t = blockIdx.x * blockDim.x + threadIdx.x;

    // zero the hist+cnt region (replaces a hipMemsetAsync dispatch)
    for (int i = t; i < histW; i += gridDim.x * blockDim.x) histz[i] = 0u;

    if (t >= B * P) return;
    int b = t / P;
    int p = t - b * P;

    // softmax over class dim (C small)
    float x[8];
    float m = -INFINITY;
    for (int c = 0; c < C; ++c) {
        x[c] = conf[((size_t)b * C + c) * P + p];
        m = fmaxf(m, x[c]);
    }
    float sum = 0.f;
    for (int c = 0; c < C; ++c) {
        x[c] = expf(x[c] - m);
        sum += x[c];
    }
    for (int c = 1; c < C; ++c) {
        float v = x[c] / sum;
        int bc = b * (C - 1) + (c - 1);
        scores[(size_t)bc * P + p] = v;
    }

    // decode
    float l0 = loc[((size_t)b * 4 + 0) * P + p];
    float l1 = loc[((size_t)b * 4 + 1) * P + p];
    float l2 = loc[((size_t)b * 4 + 2) * P + p];
    float l3 = loc[((size_t)b * 4 + 3) * P + p];
    float pcx = prior[(size_t)p * 4 + 0];
    float pcy = prior[(size_t)p * 4 + 1];
    float pw  = prior[(size_t)p * 4 + 2];
    float ph  = prior[(size_t)p * 4 + 3];

    float cx = pcx + (l0 * 0.1f) * pw;
    float cy = pcy + (l1 * 0.1f) * ph;
    float w  = pw * expf(l2 * 0.2f);
    float h  = ph * expf(l3 * 0.2f);

    float4 o4 = make_float4(cx, cy, w, h);
    *(float4*)(cs + ((size_t)b * P + p) * 4) = o4;
}

// ---------------- Kernel 1b: LDS-privatized score histogram ----------------
__global__ void __launch_bounds__(256)
hist_kernel(const float* __restrict__ scores,
            const float* __restrict__ cthp,
            unsigned* __restrict__ hist,     // [NBC][HB]
            int P) {
    __shared__ unsigned sh[HB / 2];          // 32 KB (16-bit packed counters)
    int bc  = blockIdx.x;
    int tid = threadIdx.x;
    float cth = *cthp;

    for (int i = tid; i < HB / 2; i += 256) sh[i] = 0u;
    __syncthreads();

    int chunk = (P + HCHUNK - 1) / HCHUNK;
    int lo = blockIdx.y * chunk;
    int hi = lo + chunk; if (hi > P) hi = P;
    const float* s = scores + (size_t)bc * P;
    for (int p = lo + tid; p < hi; p += 256) {
        float v = s[p];
        if (v >= cth) {
            unsigned bin = __float_as_uint(v) >> HSHIFT;
            atomicAdd(&sh[bin >> 1], (bin & 1u) ? 65536u : 1u);
        }
    }
    __syncthreads();

    unsigned* h = hist + (size_t)bc * HB;
    for (int i = tid; i < HB / 2; i += 256) {
        unsigned v = sh[i];
        if (v & 0xFFFFu)  atomicAdd(&h[2 * i],     v & 0xFFFFu);
        if (v >> 16)      atomicAdd(&h[2 * i + 1], v >> 16);
    }
}

// ---------------- Kernel 2: per-(b,c) pivot bin via parallel suffix scan ----------------
__global__ void __launch_bounds__(256)
pivot_kernel(const unsigned* __restrict__ hist, unsigned* __restrict__ pivot) {
    int bc  = blockIdx.x;
    int t   = threadIdx.x;
    const unsigned* h = hist + (size_t)bc * HB;
    __shared__ unsigned T[256];

    const int per = HB / 256;                // 64 bins per thread
    int base = t * per;
    unsigned S = 0;
    for (int i = 0; i < per; ++i) S += h[base + i];
    T[t] = S;
    __syncthreads();

    for (int d = 1; d < 256; d <<= 1) {
        unsigned add = (t + d < 256) ? T[t + d] : 0u;
        __syncthreads();
        T[t] += add;
        __syncthreads();
    }

    unsigned Tt = T[t];
    unsigned Tn = (t + 1 < 256) ? T[t + 1] : 0u;
    if (Tt >= (unsigned)KTOP && Tn < (unsigned)KTOP) {
        unsigned cum = Tn;
        for (int i = per - 1; i >= 0; --i) {
            cum += h[base + i];
            if (cum >= (unsigned)KTOP) { pivot[bc] = (unsigned)(base + i); break; }
        }
    }
    if (t == 0 && T[0] < (unsigned)KTOP) pivot[bc] = 0u;   // fewer than KTOP valid: take all
}

// ---------------- Kernel 3: gather with BLOCK-aggregated allocation ----------------
__global__ void __launch_bounds__(256)
gather_kernel(const float* __restrict__ scores,
              const unsigned* __restrict__ pivot,
              unsigned* __restrict__ cnt,
              ull* __restrict__ cand,
              const float* __restrict__ cthp, int P) {
    __shared__ unsigned wsum[4];
    __shared__ unsigned s_base;
    int bc = blockIdx.x;
    const float* s = scores + (size_t)bc * P;
    float cth = *cthp;
    unsigned pv = pivot[bc];
    int nchunk = gridDim.y;
    int chunk = (P + nchunk - 1) / nchunk;
    int lo = blockIdx.y * chunk;
    int hi = lo + chunk; if (hi > P) hi = P;
    int tid  = threadIdx.x;
    int lane = tid & 63;
    int wid  = tid >> 6;

    // phase 1: count
    unsigned mycnt = 0;
    for (int p = lo + tid; p < hi; p += 256) {
        float v = s[p];
        unsigned k = __float_as_uint(v);
        if (v >= cth && (k >> HSHIFT) >= pv) ++mycnt;
    }
    unsigned x = mycnt;
    for (int d = 1; d < 64; d <<= 1) {
        unsigned y = (unsigned)__shfl_up((int)x, d);
        if (lane >= d) x += y;
    }
    if (lane == 63) wsum[wid] = x;
    __syncthreads();
    if (tid == 0) {
        unsigned tot = 0;
        for (int w = 0; w < 4; ++w) { unsigned t2 = wsum[w]; wsum[w] = tot; tot += t2; }
        s_base = tot ? atomicAdd(&cnt[bc], tot) : 0u;
    }
    __syncthreads();
    unsigned off = s_base + wsum[wid] + (x - mycnt);

    // phase 2: write (chunk is L2-hot from phase 1)
    ull* cb = cand + (size_t)bc * CAP;
    for (int p = lo + tid; p < hi; p += 256) {
        float v = s[p];
        unsigned k = __float_as_uint(v);
        if (v >= cth && (k >> HSHIFT) >= pv) {
            if (off < CAP)
                cb[off] = ((ull)k << 32) | (unsigned)(~(unsigned)p);
            ++off;
        }
    }
}

// ---------------- Kernel 4: per-(b,c) bitonic sort + export sorted boxes ----------------
__global__ void __launch_bounds__(1024)
sort_kernel(const ull* __restrict__ cand,
            const unsigned* __restrict__ cnt,
            const float* __restrict__ cs,
            float* __restrict__ rows,      // [NBC][KTOP][5] score,cx,cy,w,h
            float* __restrict__ bx1, float* __restrict__ by1,
            float* __restrict__ bx2, float* __restrict__ by2,
            float* __restrict__ bar,       // SoA [NBC][ROWS]
            int* __restrict__ nselArr,
            int P, int Cfg) {
#pragma clang fp contract(off)
    int bc  = blockIdx.x;
    int b   = bc / Cfg;
    int tid = threadIdx.x;
    __shared__ ull sbuf[CAP];

    int M = (int)cnt[bc]; if (M > CAP) M = CAP;
    int nsel = M < KTOP ? M : KTOP;
    if (tid == 0) nselArr[bc] = nsel;

    int n = 1024;
    while (n < M) n <<= 1;
    for (int i = tid; i < n; i += 1024)
        sbuf[i] = (i < M) ? cand[(size_t)bc * CAP + i] : 0ull;
    __syncthreads();

    for (unsigned k = 2; k <= (unsigned)n; k <<= 1) {
        for (unsigned j = k >> 1; j > 0; j >>= 1) {
            for (unsigned i = tid; i < (unsigned)n; i += 1024) {
                unsigned ixj = i ^ j;
                if (ixj > i) {
                    bool up = ((i & k) == 0u);
                    ull a = sbuf[i], bb = sbuf[ixj];
                    if ((a > bb) == up) { sbuf[i] = bb; sbuf[ixj] = a; }
                }
            }
            __syncthreads();
        }
    }

    for (int r = tid; r < nsel; r += 1024) {
        ull e = sbuf[n - 1 - r];
        float sc = __uint_as_float((unsigned)(e >> 32));
        int idx = (int)(~(unsigned)e);
        const float* c4 = cs + ((size_t)b * P + idx) * 4;
        float cx = c4[0], cy = c4[1], w = c4[2], h = c4[3];
        float x1 = cx - w / 2.f, y1 = cy - h / 2.f;
        float x2 = cx + w / 2.f, y2 = cy + h / 2.f;
        size_t sb = (size_t)bc * ROWS + r;
        bx1[sb] = x1; by1[sb] = y1; bx2[sb] = x2; by2[sb] = y2;
        bar[sb] = fmaxf(x2 - x1, 0.f) * fmaxf(y2 - y1, 0.f);
        float* rr = rows + ((size_t)bc * KTOP + r) * 5;
        rr[0] = sc; rr[1] = cx; rr[2] = cy; rr[3] = w; rr[4] = h;
    }
}

// ---------------- Kernel 5: GPU-wide suppression bitmask matrix ----------------
__global__ void __launch_bounds__(1024)
mask_kernel(const float* __restrict__ bx1, const float* __restrict__ by1,
            const float* __restrict__ bx2, const float* __restrict__ by2,
            const float* __restrict__ bar,
            const int* __restrict__ nselArr,
            const float* __restrict__ nthp,
            ull* __restrict__ mask) {       // [NBC][ROWS][WORDS]
#pragma clang fp contract(off)
    int bc   = blockIdx.x;
    int tile = blockIdx.y;                  // 16 tiles x 64 rows
    int tid  = threadIdx.x;
    int nsel = nselArr[bc];
    float nth = *nthp;

    __shared__ float sx1[ROWS], sy1[ROWS], sx2[ROWS], sy2[ROWS], sar[ROWS];
    size_t sb = (size_t)bc * ROWS;
    if (tid < nsel) {
        sx1[tid] = bx1[sb + tid]; sy1[tid] = by1[sb + tid];
        sx2[tid] = bx2[sb + tid]; sy2[tid] = by2[sb + tid];
        sar[tid] = bar[sb + tid];
    }
    __syncthreads();

    int i = tile * 64 + (tid >> 4);
    int w = tid & 15;
    if (i >= nsel) {
        mask[(((size_t)bc * ROWS + i) << 4) + w] = 0ull;   // zero-fill padding rows
        return;
    }

    float xi1 = sx1[i], yi1 = sy1[i], xi2 = sx2[i], yi2 = sy2[i], ai = sar[i];
    ull bits = 0ull;
    int j0 = w << 6;
    for (int jj0 = 0; jj0 < 64; ++jj0) {
        int jj = (jj0 + (w << 2)) & 63;
        int j = j0 + jj;
        if (j > i && j < nsel) {
            float ww = fmaxf(fminf(xi2, sx2[j]) - fmaxf(xi1, sx1[j]), 0.f);
            float hh = fmaxf(fminf(yi2, sy2[j]) - fmaxf(yi1, sy1[j]), 0.f);
            float inter = ww * hh;
            float uni = ai + sar[j] - inter;
            float iou = inter / fmaxf(uni, 1e-12f);
            if (iou > nth) bits |= 1ull << jj;
        }
    }
    mask[(((size_t)bc * ROWS + i) << 4) + w] = bits;
}

// ---------------- Kernel 6: fused serial reduce + parallel pack ----------------
// 256 threads. Wave 0 runs the serial greedy reduce (R10 structure: depth-2
// register prefetch, LDS double-buffer, broadcast-fed serial loop); waves 1-3
// wait at the barrier. Then ALL threads compact kept rows and zero-fill rows
// >= nkept, so d_out needs no memset.
__device__ __forceinline__ void nms_chunk_body(
    int c, int nchunk, int lane, int g, int w,
    const ull* __restrict__ mrow, ull* sm,
    ull (&pr)[16], ull (&st)[16], ull& S)
{
    int cb = (c & 1) << 10;
    int nb = ((c + 1) & 1) << 10;
    if (c + 2 < nchunk) {                    // prefetch chunk c+2
        #pragma unroll
        for (int k = 0; k < 16; ++k)
            pr[k] = mrow[(size_t)(c + 2) * 1024 + k * 64 + lane];
    }

    // ---- serial greedy on word c (all lanes redundant; broadcast LDS reads) ----
    ull cur = __shfl(S, c);
    #pragma unroll
    for (int i = 0; i < 64; ++i) {
        ull di   = sm[cb + (i << 4) + c];
        ull supm = (ull)((long long)(cur << (63 - i)) >> 63);  // all-ones iff rank i suppressed
        cur |= di & ~supm;
    }
    ull kbits = ~cur;                        // kept = not suppressed

    // ---- bulk apply: lane (g,w) ORs kept rows of group g, word w ----
    unsigned sub = (unsigned)((kbits >> (g << 4)) & 0xFFFFull);
    int rbase2 = cb + (g << 8) + w;
    ull part = 0ull;
    #pragma unroll
    for (int i = 0; i < 16; ++i) {
        ull v = sm[rbase2 + (i << 4)];       // unconditional, pipelined
        part |= v & (ull)(0ll - (long long)((sub >> i) & 1u));
    }
    part |= __shfl_xor(part, 16);
    part |= __shfl_xor(part, 32);
    S |= part;                               // lanes 0..15 meaningful
    if (lane == c) S = cur;                  // finalize word c

    if (c + 1 < nchunk) {                    // stage chunk c+1 into the other LDS buffer
        #pragma unroll
        for (int k = 0; k < 16; ++k) sm[nb + k * 64 + lane] = st[k];
    }
}

__global__ void __launch_bounds__(256)
reduce_pack_kernel(const ull* __restrict__ mask,
                   const int* __restrict__ nselArr,
                   const float* __restrict__ rows,
                   float* __restrict__ out) {
    int bc  = blockIdx.x;
    int tid = threadIdx.x;
    int nsel = nselArr[bc];
    const ull* mrow = mask + ((size_t)bc * ROWS << 4);

    __shared__ ull sm[2048];                // 2 x (64 rows x 16 words) = 16 KB
    __shared__ ull kw[WORDS];
    __shared__ unsigned pref[WORDS + 1];

    if (tid < 64) {                          // wave 0: serial reduce
        int lane = tid;
        int nchunk = (nsel + 63) >> 6;       // <= 16
        ull S = 0ull;
        int g = lane >> 4;
        int w = lane & 15;

        ull ra[16], rb[16];
        if (nchunk > 0) {
            #pragma unroll
            for (int k = 0; k < 16; ++k) ra[k] = mrow[k * 64 + lane];
            if (nchunk > 1) {
                #pragma unroll
                for (int k = 0; k < 16; ++k) rb[k] = mrow[1024 + k * 64 + lane];
            }
            #pragma unroll
            for (int k = 0; k < 16; ++k) sm[k * 64 + lane] = ra[k];

            #pragma unroll 1
            for (int cc = 0; cc < 8; ++cc) {
                int c0 = cc << 1;
                if (c0 >= nchunk) break;
                nms_chunk_body(c0, nchunk, lane, g, w, mrow, sm, ra, rb, S);
                int c1 = c0 + 1;
                if (c1 >= nchunk) break;
                nms_chunk_body(c1, nchunk, lane, g, w, mrow, sm, rb, ra, S);
            }
        }

        if (lane < WORDS) {
            int base_i = lane << 6;
            ull valid = 0ull;
            int rem = nsel - base_i;
            if (rem > 0) valid = (rem >= 64) ? ~0ull : ((1ull << rem) - 1ull);
            kw[lane] = (~S) & valid;
        }
    }
    __syncthreads();

    if (tid == 0) {
        unsigned c = 0;
        for (int w = 0; w < WORDS; ++w) { pref[w] = c; c += (unsigned)__popcll(kw[w]); }
        pref[WORDS] = c;
    }
    __syncthreads();
    unsigned tot = pref[WORDS];

    const float* rbase = rows + (size_t)bc * KTOP * 5;
    float* obase = out + (size_t)bc * KTOP * 5;
    for (int r = tid; r < KTOP; r += 256) {
        ull wv = kw[r >> 6];
        if ((wv >> (r & 63)) & 1ull) {
            int pos = (int)pref[r >> 6] + __popcll(wv & ((1ull << (r & 63)) - 1ull));
            const float* rr = rbase + r * 5;
            float* oo = obase + pos * 5;
            oo[0] = rr[0]; oo[1] = rr[1]; oo[2] = rr[2]; oo[3] = rr[3]; oo[4] = rr[4];
        }
        if (r >= (int)tot) {                 // zero-fill tail (replaces out memset)
            float* oo = obase + r * 5;
            oo[0] = 0.f; oo[1] = 0.f; oo[2] = 0.f; oo[3] = 0.f; oo[4] = 0.f;
        }
    }
}

// ------------------------------- launcher -------------------------------
extern "C" void kernel_launch(void* const* d_in, const int* in_sizes, int n_in,
                              void* d_out, int out_size, void* d_ws, size_t ws_size,
                              hipStream_t stream) {
    (void)n_in; (void)out_size; (void)ws_size;
    const float* loc   = (const float*)d_in[0];
    const float* conf  = (const float*)d_in[1];
    const float* prior = (const float*)d_in[2];
    const float* cth   = (const float*)d_in[3];
    const float* nth   = (const float*)d_in[4];
    float* out = (float*)d_out;

    int P   = in_sizes[2] / 4;
    int B   = in_sizes[0] / (4 * P);
    int C   = in_sizes[1] / (B * P);
    int Cfg = C - 1;
    int NBC = B * Cfg;

    // ---- carve workspace (256B aligned sections; 8B types first) ----
    char* base = (char*)d_ws;
    size_t off = 0;
    auto carve = [&](size_t bytes) { char* p = base + off; off = (off + bytes + 255) & ~(size_t)255; return p; };

    ull*      cand   = (ull*)     carve((size_t)NBC * CAP * 8);
    ull*      mask   = (ull*)     carve((size_t)NBC * ROWS * WORDS * 8);
    float*    scores = (float*)   carve((size_t)NBC * P * 4);
    float*    cs     = (float*)   carve((size_t)B * P * 4 * 4);
    float*    rows   = (float*)   carve((size_t)NBC * KTOP * 5 * 4);
    float*    bx1    = (float*)   carve((size_t)NBC * ROWS * 4);
    float*    by1    = (float*)   carve((size_t)NBC * ROWS * 4);
    float*    bx2    = (float*)   carve((size_t)NBC * ROWS * 4);
    float*    by2    = (float*)   carve((size_t)NBC * ROWS * 4);
    float*    bar    = (float*)   carve((size_t)NBC * ROWS * 4);
    unsigned* hist   = (unsigned*)carve((size_t)NBC * HB * 4 + (size_t)NBC * 4);  // hist + cnt contiguous
    unsigned* cnt    = hist + (size_t)NBC * HB;
    unsigned* pivot  = (unsigned*)carve((size_t)NBC * 4);
    int*      nselA  = (int*)     carve((size_t)NBC * 4);

    int histW = NBC * HB + NBC;              // words to zero (hist + cnt)

    int n1 = B * P;
    decode_kernel<<<(n1 + 255) / 256, 256, 0, stream>>>(loc, conf, prior, scores, cs, hist, histW, B, C, P);
    hist_kernel<<<dim3(NBC, HCHUNK), 256, 0, stream>>>(scores, cth, hist, P);
    pivot_kernel<<<NBC, 256, 0, stream>>>(hist, pivot);
    gather_kernel<<<dim3(NBC, 32), 256, 0, stream>>>(scores, pivot, cnt, cand, cth, P);
    sort_kernel<<<NBC, 1024, 0, stream>>>(cand, cnt, cs, rows, bx1, by1, bx2, by2, bar, nselA, P, Cfg);
    mask_kernel<<<dim3(NBC, ROWS / 64), 1024, 0, stream>>>(bx1, by1, bx2, by2, bar, nselA, nth, mask);
    reduce_pack_kernel<<<NBC, 256, 0, stream>>>(mask, nselA, rows, out);
}

// Round 12
// 221.360 us; speedup vs baseline: 1.1287x; 1.0191x over previous
//
#include <hip/hip_runtime.h>
#include <cstdint>
#include <cstddef>

typedef unsigned long long ull;

#define KTOP   1000
#define CAP    4096      // candidate gather capacity per (b,c)
#define HBITS  14
#define HB     (1 << HBITS)          // 16384 histogram bins (top-14 float bits)
#define HSHIFT (32 - HBITS)
#define ROWS   1024      // padded rank capacity (>= KTOP)
#define WORDS  16        // 1024 / 64 bitmask words per row
#define HCHUNK 16        // score chunks per (b,c) for the LDS histogram kernel

// ---------------- Kernel 1: softmax + SSD decode + hist zeroing ----------------
__global__ void decode_kernel(const float* __restrict__ loc,
                              const float* __restrict__ conf,
                              const float* __restrict__ prior,
                              float* __restrict__ scores,   // [B*Cfg][P]
                              float* __restrict__ cs,       // [B][P][4] center-size
                              unsigned* __restrict__ histz, // hist+cnt region to zero
                              int histW,
                              int B, int C, int P) {
#pragma clang fp contract(off)
    int t = blockIdx.x * blockDim.x + threadIdx.x;

    // zero the hist+cnt region (replaces a hipMemsetAsync dispatch)
    for (int i = t; i < histW; i += gridDim.x * blockDim.x) histz[i] = 0u;

    if (t >= B * P) return;
    int b = t / P;
    int p = t - b * P;

    // softmax over class dim (C small)
    float x[8];
    float m = -INFINITY;
    for (int c = 0; c < C; ++c) {
        x[c] = conf[((size_t)b * C + c) * P + p];
        m = fmaxf(m, x[c]);
    }
    float sum = 0.f;
    for (int c = 0; c < C; ++c) {
        x[c] = expf(x[c] - m);
        sum += x[c];
    }
    for (int c = 1; c < C; ++c) {
        float v = x[c] / sum;
        int bc = b * (C - 1) + (c - 1);
        scores[(size_t)bc * P + p] = v;
    }

    // decode
    float l0 = loc[((size_t)b * 4 + 0) * P + p];
    float l1 = loc[((size_t)b * 4 + 1) * P + p];
    float l2 = loc[((size_t)b * 4 + 2) * P + p];
    float l3 = loc[((size_t)b * 4 + 3) * P + p];
    float4 pr4 = *(const float4*)(prior + (size_t)p * 4);

    float cx = pr4.x + (l0 * 0.1f) * pr4.z;
    float cy = pr4.y + (l1 * 0.1f) * pr4.w;
    float w  = pr4.z * expf(l2 * 0.2f);
    float h  = pr4.w * expf(l3 * 0.2f);

    *(float4*)(cs + ((size_t)b * P + p) * 4) = make_float4(cx, cy, w, h);
}

// ---------------- Kernel 1b: LDS-privatized score histogram ----------------
__global__ void __launch_bounds__(256)
hist_kernel(const float* __restrict__ scores,
            const float* __restrict__ cthp,
            unsigned* __restrict__ hist,     // [NBC][HB]
            int P) {
    __shared__ unsigned sh[HB / 2];          // 32 KB (16-bit packed counters)
    int bc  = blockIdx.x;
    int tid = threadIdx.x;
    float cth = *cthp;

    for (int i = tid; i < HB / 2; i += 256) sh[i] = 0u;
    __syncthreads();

    int chunk = (P + HCHUNK - 1) / HCHUNK;
    int lo = blockIdx.y * chunk;
    int hi = lo + chunk; if (hi > P) hi = P;
    const float* s = scores + (size_t)bc * P;
    for (int p = lo + tid; p < hi; p += 256) {
        float v = s[p];
        if (v >= cth) {
            unsigned bin = __float_as_uint(v) >> HSHIFT;
            atomicAdd(&sh[bin >> 1], (bin & 1u) ? 65536u : 1u);
        }
    }
    __syncthreads();

    unsigned* h = hist + (size_t)bc * HB;
    for (int i = tid; i < HB / 2; i += 256) {
        unsigned v = sh[i];
        if (v & 0xFFFFu)  atomicAdd(&h[2 * i],     v & 0xFFFFu);
        if (v >> 16)      atomicAdd(&h[2 * i + 1], v >> 16);
    }
}

// ---------------- Kernel 2: per-(b,c) pivot bin via parallel suffix scan ----------------
__global__ void __launch_bounds__(256)
pivot_kernel(const unsigned* __restrict__ hist, unsigned* __restrict__ pivot) {
    int bc  = blockIdx.x;
    int t   = threadIdx.x;
    const unsigned* h = hist + (size_t)bc * HB;
    __shared__ unsigned T[256];

    const int per = HB / 256;                // 64 bins per thread
    int base = t * per;
    unsigned S = 0;
    for (int i = 0; i < per; ++i) S += h[base + i];
    T[t] = S;
    __syncthreads();

    for (int d = 1; d < 256; d <<= 1) {
        unsigned add = (t + d < 256) ? T[t + d] : 0u;
        __syncthreads();
        T[t] += add;
        __syncthreads();
    }

    unsigned Tt = T[t];
    unsigned Tn = (t + 1 < 256) ? T[t + 1] : 0u;
    if (Tt >= (unsigned)KTOP && Tn < (unsigned)KTOP) {
        unsigned cum = Tn;
        for (int i = per - 1; i >= 0; --i) {
            cum += h[base + i];
            if (cum >= (unsigned)KTOP) { pivot[bc] = (unsigned)(base + i); break; }
        }
    }
    if (t == 0 && T[0] < (unsigned)KTOP) pivot[bc] = 0u;   // fewer than KTOP valid: take all
}

// ---------------- Kernel 3: gather with BLOCK-aggregated allocation ----------------
__global__ void __launch_bounds__(256)
gather_kernel(const float* __restrict__ scores,
              const unsigned* __restrict__ pivot,
              unsigned* __restrict__ cnt,
              ull* __restrict__ cand,
              const float* __restrict__ cthp, int P) {
    __shared__ unsigned wsum[4];
    __shared__ unsigned s_base;
    int bc = blockIdx.x;
    const float* s = scores + (size_t)bc * P;
    float cth = *cthp;
    unsigned pv = pivot[bc];
    int nchunk = gridDim.y;
    int chunk = (P + nchunk - 1) / nchunk;
    int lo = blockIdx.y * chunk;
    int hi = lo + chunk; if (hi > P) hi = P;
    int tid  = threadIdx.x;
    int lane = tid & 63;
    int wid  = tid >> 6;

    // phase 1: count
    unsigned mycnt = 0;
    for (int p = lo + tid; p < hi; p += 256) {
        float v = s[p];
        unsigned k = __float_as_uint(v);
        if (v >= cth && (k >> HSHIFT) >= pv) ++mycnt;
    }
    unsigned x = mycnt;
    for (int d = 1; d < 64; d <<= 1) {
        unsigned y = (unsigned)__shfl_up((int)x, d);
        if (lane >= d) x += y;
    }
    if (lane == 63) wsum[wid] = x;
    __syncthreads();
    if (tid == 0) {
        unsigned tot = 0;
        for (int w = 0; w < 4; ++w) { unsigned t2 = wsum[w]; wsum[w] = tot; tot += t2; }
        s_base = tot ? atomicAdd(&cnt[bc], tot) : 0u;
    }
    __syncthreads();
    unsigned off = s_base + wsum[wid] + (x - mycnt);

    // phase 2: write (chunk is L2-hot from phase 1)
    ull* cb = cand + (size_t)bc * CAP;
    for (int p = lo + tid; p < hi; p += 256) {
        float v = s[p];
        unsigned k = __float_as_uint(v);
        if (v >= cth && (k >> HSHIFT) >= pv) {
            if (off < CAP)
                cb[off] = ((ull)k << 32) | (unsigned)(~(unsigned)p);
            ++off;
        }
    }
}

// ---------------- Kernel 4: per-(b,c) bitonic sort + export sorted boxes ----------------
__global__ void __launch_bounds__(1024)
sort_kernel(const ull* __restrict__ cand,
            const unsigned* __restrict__ cnt,
            const float* __restrict__ cs,
            float* __restrict__ rows,      // [NBC][KTOP][5] score,cx,cy,w,h
            float4* __restrict__ pbox,     // [NBC][ROWS] point-form x1,y1,x2,y2
            float* __restrict__ bar,       // [NBC][ROWS] area
            int* __restrict__ nselArr,
            int P, int Cfg) {
#pragma clang fp contract(off)
    int bc  = blockIdx.x;
    int b   = bc / Cfg;
    int tid = threadIdx.x;
    __shared__ ull sbuf[CAP];

    int M = (int)cnt[bc]; if (M > CAP) M = CAP;
    int nsel = M < KTOP ? M : KTOP;
    if (tid == 0) nselArr[bc] = nsel;

    int n = 1024;
    while (n < M) n <<= 1;
    for (int i = tid; i < n; i += 1024)
        sbuf[i] = (i < M) ? cand[(size_t)bc * CAP + i] : 0ull;
    __syncthreads();

    for (unsigned k = 2; k <= (unsigned)n; k <<= 1) {
        for (unsigned j = k >> 1; j > 0; j >>= 1) {
            for (unsigned i = tid; i < (unsigned)n; i += 1024) {
                unsigned ixj = i ^ j;
                if (ixj > i) {
                    bool up = ((i & k) == 0u);
                    ull a = sbuf[i], bb = sbuf[ixj];
                    if ((a > bb) == up) { sbuf[i] = bb; sbuf[ixj] = a; }
                }
            }
            __syncthreads();
        }
    }

    for (int r = tid; r < nsel; r += 1024) {
        ull e = sbuf[n - 1 - r];
        float sc = __uint_as_float((unsigned)(e >> 32));
        int idx = (int)(~(unsigned)e);
        const float* c4 = cs + ((size_t)b * P + idx) * 4;
        float cx = c4[0], cy = c4[1], w = c4[2], h = c4[3];
        float x1 = cx - w / 2.f, y1 = cy - h / 2.f;
        float x2 = cx + w / 2.f, y2 = cy + h / 2.f;
        size_t sb = (size_t)bc * ROWS + r;
        pbox[sb] = make_float4(x1, y1, x2, y2);
        bar[sb]  = fmaxf(x2 - x1, 0.f) * fmaxf(y2 - y1, 0.f);
        float* rr = rows + ((size_t)bc * KTOP + r) * 5;
        rr[0] = sc; rr[1] = cx; rr[2] = cy; rr[3] = w; rr[4] = h;
    }
}

// ---------------- Kernel 5: suppression bitmask via per-lane-j + ballot ----------------
// Wave wv owns 4 rows; lane = j within a 64-wide column group. The 64-bit mask
// word is produced directly by __ballot — no per-lane bit accumulation, no
// redundant reads. j-data (float4 box + area) loaded ONCE per w, reused for
// all 4 rows. Rows >= nsel get zero words automatically (predicate j<nsel).
__global__ void __launch_bounds__(1024)
mask_kernel(const float4* __restrict__ pbox,
            const float* __restrict__ bar,
            const int* __restrict__ nselArr,
            const float* __restrict__ nthp,
            ull* __restrict__ mask) {       // [NBC][ROWS][WORDS]
#pragma clang fp contract(off)
    int bc   = blockIdx.x;
    int tile = blockIdx.y;                  // 16 tiles x 64 rows
    int tid  = threadIdx.x;
    int nsel = nselArr[bc];
    float nth = *nthp;

    __shared__ float4 sbox[ROWS];           // 16 KB
    __shared__ float  sar[ROWS];            // 4 KB
    size_t sb = (size_t)bc * ROWS;
    sbox[tid] = pbox[sb + tid];
    sar[tid]  = bar[sb + tid];
    __syncthreads();

    int wv   = tid >> 6;                    // wave 0..15
    int lane = tid & 63;
    int i0   = tile * 64 + (wv << 2);       // 4 rows per wave

    float4 bi[4]; float ai[4];
    #pragma unroll
    for (int r = 0; r < 4; ++r) { bi[r] = sbox[i0 + r]; ai[r] = sar[i0 + r]; }   // broadcast

    ull rowbits[4] = {0ull, 0ull, 0ull, 0ull};
    for (int w = 0; w < WORDS; ++w) {
        int j = (w << 6) + lane;
        float4 bj = sbox[j];
        float  aj = sar[j];
        #pragma unroll
        for (int r = 0; r < 4; ++r) {
            int i = i0 + r;
            float ww = fmaxf(fminf(bi[r].z, bj.z) - fmaxf(bi[r].x, bj.x), 0.f);
            float hh = fmaxf(fminf(bi[r].w, bj.w) - fmaxf(bi[r].y, bj.y), 0.f);
            float inter = ww * hh;
            float uni = ai[r] + aj - inter;
            float iou = inter / fmaxf(uni, 1e-12f);
            bool ok = (j > i) && (j < nsel) && (iou > nth);
            ull bits = __ballot(ok);
            if (lane == w) rowbits[r] = bits;
        }
    }
    #pragma unroll
    for (int r = 0; r < 4; ++r)
        if (lane < WORDS)
            mask[(((size_t)bc * ROWS + (i0 + r)) << 4) + lane] = rowbits[r];
}

// ---------------- Kernel 6: fused serial reduce + parallel pack ----------------
__device__ __forceinline__ void nms_chunk_body(
    int c, int nchunk, int lane, int g, int w,
    const ull* __restrict__ mrow, ull* sm,
    ull (&pr)[16], ull (&st)[16], ull& S)
{
    int cb = (c & 1) << 10;
    int nb = ((c + 1) & 1) << 10;
    if (c + 2 < nchunk) {                    // prefetch chunk c+2
        #pragma unroll
        for (int k = 0; k < 16; ++k)
            pr[k] = mrow[(size_t)(c + 2) * 1024 + k * 64 + lane];
    }

    // ---- serial greedy on word c (all lanes redundant; broadcast LDS reads) ----
    ull cur = __shfl(S, c);
    #pragma unroll
    for (int i = 0; i < 64; ++i) {
        ull di   = sm[cb + (i << 4) + c];
        ull supm = (ull)((long long)(cur << (63 - i)) >> 63);  // all-ones iff rank i suppressed
        cur |= di & ~supm;
    }
    ull kbits = ~cur;                        // kept = not suppressed

    // ---- bulk apply: lane (g,w) ORs kept rows of group g, word w ----
    unsigned sub = (unsigned)((kbits >> (g << 4)) & 0xFFFFull);
    int rbase2 = cb + (g << 8) + w;
    ull part = 0ull;
    #pragma unroll
    for (int i = 0; i < 16; ++i) {
        ull v = sm[rbase2 + (i << 4)];       // unconditional, pipelined
        part |= v & (ull)(0ll - (long long)((sub >> i) & 1u));
    }
    part |= __shfl_xor(part, 16);
    part |= __shfl_xor(part, 32);
    S |= part;                               // lanes 0..15 meaningful
    if (lane == c) S = cur;                  // finalize word c

    if (c + 1 < nchunk) {                    // stage chunk c+1 into the other LDS buffer
        #pragma unroll
        for (int k = 0; k < 16; ++k) sm[nb + k * 64 + lane] = st[k];
    }
}

__global__ void __launch_bounds__(256)
reduce_pack_kernel(const ull* __restrict__ mask,
                   const int* __restrict__ nselArr,
                   const float* __restrict__ rows,
                   float* __restrict__ out) {
    int bc  = blockIdx.x;
    int tid = threadIdx.x;
    int nsel = nselArr[bc];
    const ull* mrow = mask + ((size_t)bc * ROWS << 4);

    __shared__ ull sm[2048];                // 2 x (64 rows x 16 words) = 16 KB
    __shared__ ull kw[WORDS];
    __shared__ unsigned pref[WORDS + 1];

    if (tid < 64) {                          // wave 0: serial reduce
        int lane = tid;
        int nchunk = (nsel + 63) >> 6;       // <= 16
        ull S = 0ull;
        int g = lane >> 4;
        int w = lane & 15;

        ull ra[16], rb[16];
        if (nchunk > 0) {
            #pragma unroll
            for (int k = 0; k < 16; ++k) ra[k] = mrow[k * 64 + lane];
            if (nchunk > 1) {
                #pragma unroll
                for (int k = 0; k < 16; ++k) rb[k] = mrow[1024 + k * 64 + lane];
            }
            #pragma unroll
            for (int k = 0; k < 16; ++k) sm[k * 64 + lane] = ra[k];

            #pragma unroll 1
            for (int cc = 0; cc < 8; ++cc) {
                int c0 = cc << 1;
                if (c0 >= nchunk) break;
                nms_chunk_body(c0, nchunk, lane, g, w, mrow, sm, ra, rb, S);
                int c1 = c0 + 1;
                if (c1 >= nchunk) break;
                nms_chunk_body(c1, nchunk, lane, g, w, mrow, sm, rb, ra, S);
            }
        }

        if (lane < WORDS) {
            int base_i = lane << 6;
            ull valid = 0ull;
            int rem = nsel - base_i;
            if (rem > 0) valid = (rem >= 64) ? ~0ull : ((1ull << rem) - 1ull);
            kw[lane] = (~S) & valid;
        }
    }
    __syncthreads();

    if (tid == 0) {
        unsigned c = 0;
        for (int w = 0; w < WORDS; ++w) { pref[w] = c; c += (unsigned)__popcll(kw[w]); }
        pref[WORDS] = c;
    }
    __syncthreads();
    unsigned tot = pref[WORDS];

    const float* rbase = rows + (size_t)bc * KTOP * 5;
    float* obase = out + (size_t)bc * KTOP * 5;
    for (int r = tid; r < KTOP; r += 256) {
        ull wv = kw[r >> 6];
        if ((wv >> (r & 63)) & 1ull) {
            int pos = (int)pref[r >> 6] + __popcll(wv & ((1ull << (r & 63)) - 1ull));
            const float* rr = rbase + r * 5;
            float* oo = obase + pos * 5;
            oo[0] = rr[0]; oo[1] = rr[1]; oo[2] = rr[2]; oo[3] = rr[3]; oo[4] = rr[4];
        }
        if (r >= (int)tot) {                 // zero-fill tail (replaces out memset)
            float* oo = obase + r * 5;
            oo[0] = 0.f; oo[1] = 0.f; oo[2] = 0.f; oo[3] = 0.f; oo[4] = 0.f;
        }
    }
}

// ------------------------------- launcher -------------------------------
extern "C" void kernel_launch(void* const* d_in, const int* in_sizes, int n_in,
                              void* d_out, int out_size, void* d_ws, size_t ws_size,
                              hipStream_t stream) {
    (void)n_in; (void)out_size; (void)ws_size;
    const float* loc   = (const float*)d_in[0];
    const float* conf  = (const float*)d_in[1];
    const float* prior = (const float*)d_in[2];
    const float* cth   = (const float*)d_in[3];
    const float* nth   = (const float*)d_in[4];
    float* out = (float*)d_out;

    int P   = in_sizes[2] / 4;
    int B   = in_sizes[0] / (4 * P);
    int C   = in_sizes[1] / (B * P);
    int Cfg = C - 1;
    int NBC = B * Cfg;

    // ---- carve workspace (256B aligned sections; widest types first) ----
    char* base = (char*)d_ws;
    size_t off = 0;
    auto carve = [&](size_t bytes) { char* p = base + off; off = (off + bytes + 255) & ~(size_t)255; return p; };

    float4*   pbox   = (float4*)  carve((size_t)NBC * ROWS * 16);
    ull*      cand   = (ull*)     carve((size_t)NBC * CAP * 8);
    ull*      mask   = (ull*)     carve((size_t)NBC * ROWS * WORDS * 8);
    float*    scores = (float*)   carve((size_t)NBC * P * 4);
    float*    cs     = (float*)   carve((size_t)B * P * 4 * 4);
    float*    rows   = (float*)   carve((size_t)NBC * KTOP * 5 * 4);
    float*    bar    = (float*)   carve((size_t)NBC * ROWS * 4);
    unsigned* hist   = (unsigned*)carve((size_t)NBC * HB * 4 + (size_t)NBC * 4);  // hist + cnt contiguous
    unsigned* cnt    = hist + (size_t)NBC * HB;
    unsigned* pivot  = (unsigned*)carve((size_t)NBC * 4);
    int*      nselA  = (int*)     carve((size_t)NBC * 4);

    int histW = NBC * HB + NBC;              // words to zero (hist + cnt)

    int n1 = B * P;
    decode_kernel<<<(n1 + 255) / 256, 256, 0, stream>>>(loc, conf, prior, scores, cs, hist, histW, B, C, P);
    hist_kernel<<<dim3(NBC, HCHUNK), 256, 0, stream>>>(scores, cth, hist, P);
    pivot_kernel<<<NBC, 256, 0, stream>>>(hist, pivot);
    gather_kernel<<<dim3(NBC, 32), 256, 0, stream>>>(scores, pivot, cnt, cand, cth, P);
    sort_kernel<<<NBC, 1024, 0, stream>>>(cand, cnt, cs, rows, pbox, bar, nselA, P, Cfg);
    mask_kernel<<<dim3(NBC, ROWS / 64), 1024, 0, stream>>>(pbox, bar, nselA, nth, mask);
    reduce_pack_kernel<<<NBC, 256, 0, stream>>>(mask, nselA, rows, out);
}

// Round 13
// 210.507 us; speedup vs baseline: 1.1869x; 1.0516x over previous
//
#include <hip/hip_runtime.h>
#include <cstdint>
#include <cstddef>

typedef unsigned long long ull;

#define KTOP   1000
#define CAP    4096      // candidate gather capacity per (b,c)
#define HBITS  14
#define HB     (1 << HBITS)          // 16384 histogram bins (top-14 float bits)
#define HSHIFT (32 - HBITS)
#define ROWS   1024      // padded rank capacity (>= KTOP)
#define WORDS  16        // 1024 / 64 bitmask words per row
#define HCHUNK 16        // score chunks per (b,c) for the LDS histogram kernel

// ---------------- Kernel 1: softmax + SSD decode + hist zeroing ----------------
__global__ void decode_kernel(const float* __restrict__ loc,
                              const float* __restrict__ conf,
                              const float* __restrict__ prior,
                              float* __restrict__ scores,   // [B*Cfg][P]
                              float* __restrict__ cs,       // [B][P][4] center-size
                              unsigned* __restrict__ histz, // hist+cnt region to zero
                              int histW,
                              int B, int C, int P) {
#pragma clang fp contract(off)
    int t = blockIdx.x * blockDim.x + threadIdx.x;

    // zero the hist+cnt region (replaces a hipMemsetAsync dispatch)
    for (int i = t; i < histW; i += gridDim.x * blockDim.x) histz[i] = 0u;

    if (t >= B * P) return;
    int b = t / P;
    int p = t - b * P;

    // softmax over class dim (C small)
    float x[8];
    float m = -INFINITY;
    for (int c = 0; c < C; ++c) {
        x[c] = conf[((size_t)b * C + c) * P + p];
        m = fmaxf(m, x[c]);
    }
    float sum = 0.f;
    for (int c = 0; c < C; ++c) {
        x[c] = expf(x[c] - m);
        sum += x[c];
    }
    for (int c = 1; c < C; ++c) {
        float v = x[c] / sum;
        int bc = b * (C - 1) + (c - 1);
        scores[(size_t)bc * P + p] = v;
    }

    // decode
    float l0 = loc[((size_t)b * 4 + 0) * P + p];
    float l1 = loc[((size_t)b * 4 + 1) * P + p];
    float l2 = loc[((size_t)b * 4 + 2) * P + p];
    float l3 = loc[((size_t)b * 4 + 3) * P + p];
    float4 pr4 = *(const float4*)(prior + (size_t)p * 4);

    float cx = pr4.x + (l0 * 0.1f) * pr4.z;
    float cy = pr4.y + (l1 * 0.1f) * pr4.w;
    float w  = pr4.z * expf(l2 * 0.2f);
    float h  = pr4.w * expf(l3 * 0.2f);

    *(float4*)(cs + ((size_t)b * P + p) * 4) = make_float4(cx, cy, w, h);
}

// ---------------- Kernel 1b: LDS-privatized score histogram ----------------
__global__ void __launch_bounds__(256)
hist_kernel(const float* __restrict__ scores,
            const float* __restrict__ cthp,
            unsigned* __restrict__ hist,     // [NBC][HB]
            int P) {
    __shared__ unsigned sh[HB / 2];          // 32 KB (16-bit packed counters)
    int bc  = blockIdx.x;
    int tid = threadIdx.x;
    float cth = *cthp;

    for (int i = tid; i < HB / 2; i += 256) sh[i] = 0u;
    __syncthreads();

    int chunk = (P + HCHUNK - 1) / HCHUNK;
    int lo = blockIdx.y * chunk;
    int hi = lo + chunk; if (hi > P) hi = P;
    const float* s = scores + (size_t)bc * P;
    for (int p = lo + tid; p < hi; p += 256) {
        float v = s[p];
        if (v >= cth) {
            unsigned bin = __float_as_uint(v) >> HSHIFT;
            atomicAdd(&sh[bin >> 1], (bin & 1u) ? 65536u : 1u);
        }
    }
    __syncthreads();

    unsigned* h = hist + (size_t)bc * HB;
    for (int i = tid; i < HB / 2; i += 256) {
        unsigned v = sh[i];
        if (v & 0xFFFFu)  atomicAdd(&h[2 * i],     v & 0xFFFFu);
        if (v >> 16)      atomicAdd(&h[2 * i + 1], v >> 16);
    }
}

// ---------------- Kernel 2: per-(b,c) pivot bin via parallel suffix scan ----------------
__global__ void __launch_bounds__(256)
pivot_kernel(const unsigned* __restrict__ hist, unsigned* __restrict__ pivot) {
    int bc  = blockIdx.x;
    int t   = threadIdx.x;
    const unsigned* h = hist + (size_t)bc * HB;
    __shared__ unsigned T[256];

    const int per = HB / 256;                // 64 bins per thread
    int base = t * per;
    unsigned S = 0;
    for (int i = 0; i < per; ++i) S += h[base + i];
    T[t] = S;
    __syncthreads();

    for (int d = 1; d < 256; d <<= 1) {
        unsigned add = (t + d < 256) ? T[t + d] : 0u;
        __syncthreads();
        T[t] += add;
        __syncthreads();
    }

    unsigned Tt = T[t];
    unsigned Tn = (t + 1 < 256) ? T[t + 1] : 0u;
    if (Tt >= (unsigned)KTOP && Tn < (unsigned)KTOP) {
        unsigned cum = Tn;
        for (int i = per - 1; i >= 0; --i) {
            cum += h[base + i];
            if (cum >= (unsigned)KTOP) { pivot[bc] = (unsigned)(base + i); break; }
        }
    }
    if (t == 0 && T[0] < (unsigned)KTOP) pivot[bc] = 0u;   // fewer than KTOP valid: take all
}

// ---------------- Kernel 3: gather with BLOCK-aggregated allocation ----------------
__global__ void __launch_bounds__(256)
gather_kernel(const float* __restrict__ scores,
              const unsigned* __restrict__ pivot,
              unsigned* __restrict__ cnt,
              ull* __restrict__ cand,
              const float* __restrict__ cthp, int P) {
    __shared__ unsigned wsum[4];
    __shared__ unsigned s_base;
    int bc = blockIdx.x;
    const float* s = scores + (size_t)bc * P;
    float cth = *cthp;
    unsigned pv = pivot[bc];
    int nchunk = gridDim.y;
    int chunk = (P + nchunk - 1) / nchunk;
    int lo = blockIdx.y * chunk;
    int hi = lo + chunk; if (hi > P) hi = P;
    int tid  = threadIdx.x;
    int lane = tid & 63;
    int wid  = tid >> 6;

    // phase 1: count
    unsigned mycnt = 0;
    for (int p = lo + tid; p < hi; p += 256) {
        float v = s[p];
        unsigned k = __float_as_uint(v);
        if (v >= cth && (k >> HSHIFT) >= pv) ++mycnt;
    }
    unsigned x = mycnt;
    for (int d = 1; d < 64; d <<= 1) {
        unsigned y = (unsigned)__shfl_up((int)x, d);
        if (lane >= d) x += y;
    }
    if (lane == 63) wsum[wid] = x;
    __syncthreads();
    if (tid == 0) {
        unsigned tot = 0;
        for (int w = 0; w < 4; ++w) { unsigned t2 = wsum[w]; wsum[w] = tot; tot += t2; }
        s_base = tot ? atomicAdd(&cnt[bc], tot) : 0u;
    }
    __syncthreads();
    unsigned off = s_base + wsum[wid] + (x - mycnt);

    // phase 2: write (chunk is L2-hot from phase 1)
    ull* cb = cand + (size_t)bc * CAP;
    for (int p = lo + tid; p < hi; p += 256) {
        float v = s[p];
        unsigned k = __float_as_uint(v);
        if (v >= cth && (k >> HSHIFT) >= pv) {
            if (off < CAP)
                cb[off] = ((ull)k << 32) | (unsigned)(~(unsigned)p);
            ++off;
        }
    }
}

// ---------------- Kernel 4: per-(b,c) bitonic sort + export sorted boxes ----------------
__global__ void __launch_bounds__(1024)
sort_kernel(const ull* __restrict__ cand,
            const unsigned* __restrict__ cnt,
            const float* __restrict__ cs,
            float* __restrict__ rows,      // [NBC][KTOP][5] score,cx,cy,w,h
            float4* __restrict__ pbox,     // [NBC][ROWS] point-form x1,y1,x2,y2
            float* __restrict__ bar,       // [NBC][ROWS] area
            int* __restrict__ nselArr,
            int P, int Cfg) {
#pragma clang fp contract(off)
    int bc  = blockIdx.x;
    int b   = bc / Cfg;
    int tid = threadIdx.x;
    __shared__ ull sbuf[CAP];

    int M = (int)cnt[bc]; if (M > CAP) M = CAP;
    int nsel = M < KTOP ? M : KTOP;
    if (tid == 0) nselArr[bc] = nsel;

    int n = 1024;
    while (n < M) n <<= 1;
    for (int i = tid; i < n; i += 1024)
        sbuf[i] = (i < M) ? cand[(size_t)bc * CAP + i] : 0ull;
    __syncthreads();

    for (unsigned k = 2; k <= (unsigned)n; k <<= 1) {
        for (unsigned j = k >> 1; j > 0; j >>= 1) {
            for (unsigned i = tid; i < (unsigned)n; i += 1024) {
                unsigned ixj = i ^ j;
                if (ixj > i) {
                    bool up = ((i & k) == 0u);
                    ull a = sbuf[i], bb = sbuf[ixj];
                    if ((a > bb) == up) { sbuf[i] = bb; sbuf[ixj] = a; }
                }
            }
            __syncthreads();
        }
    }

    for (int r = tid; r < nsel; r += 1024) {
        ull e = sbuf[n - 1 - r];
        float sc = __uint_as_float((unsigned)(e >> 32));
        int idx = (int)(~(unsigned)e);
        const float* c4 = cs + ((size_t)b * P + idx) * 4;
        float cx = c4[0], cy = c4[1], w = c4[2], h = c4[3];
        float x1 = cx - w / 2.f, y1 = cy - h / 2.f;
        float x2 = cx + w / 2.f, y2 = cy + h / 2.f;
        size_t sb = (size_t)bc * ROWS + r;
        pbox[sb] = make_float4(x1, y1, x2, y2);
        bar[sb]  = fmaxf(x2 - x1, 0.f) * fmaxf(y2 - y1, 0.f);
        float* rr = rows + ((size_t)bc * KTOP + r) * 5;
        rr[0] = sc; rr[1] = cx; rr[2] = cy; rr[3] = w; rr[4] = h;
    }
}

// ---------------- Kernel 5: suppression bitmask via per-lane-j + ballot ----------------
__global__ void __launch_bounds__(1024)
mask_kernel(const float4* __restrict__ pbox,
            const float* __restrict__ bar,
            const int* __restrict__ nselArr,
            const float* __restrict__ nthp,
            ull* __restrict__ mask) {       // [NBC][ROWS][WORDS]
#pragma clang fp contract(off)
    int bc   = blockIdx.x;
    int tile = blockIdx.y;                  // 16 tiles x 64 rows
    int tid  = threadIdx.x;
    int nsel = nselArr[bc];
    float nth = *nthp;

    __shared__ float4 sbox[ROWS];           // 16 KB
    __shared__ float  sar[ROWS];            // 4 KB
    size_t sb = (size_t)bc * ROWS;
    sbox[tid] = pbox[sb + tid];
    sar[tid]  = bar[sb + tid];
    __syncthreads();

    int wv   = tid >> 6;                    // wave 0..15
    int lane = tid & 63;
    int i0   = tile * 64 + (wv << 2);       // 4 rows per wave

    float4 bi[4]; float ai[4];
    #pragma unroll
    for (int r = 0; r < 4; ++r) { bi[r] = sbox[i0 + r]; ai[r] = sar[i0 + r]; }   // broadcast

    ull rowbits[4] = {0ull, 0ull, 0ull, 0ull};
    for (int w = 0; w < WORDS; ++w) {
        int j = (w << 6) + lane;
        float4 bj = sbox[j];
        float  aj = sar[j];
        #pragma unroll
        for (int r = 0; r < 4; ++r) {
            int i = i0 + r;
            float ww = fmaxf(fminf(bi[r].z, bj.z) - fmaxf(bi[r].x, bj.x), 0.f);
            float hh = fmaxf(fminf(bi[r].w, bj.w) - fmaxf(bi[r].y, bj.y), 0.f);
            float inter = ww * hh;
            float uni = ai[r] + aj - inter;
            float iou = inter / fmaxf(uni, 1e-12f);
            bool ok = (j > i) && (j < nsel) && (iou > nth);
            ull bits = __ballot(ok);
            if (lane == w) rowbits[r] = bits;
        }
    }
    #pragma unroll
    for (int r = 0; r < 4; ++r)
        if (lane < WORDS)
            mask[(((size_t)bc * ROWS + (i0 + r)) << 4) + lane] = rowbits[r];
}

// ---------------- Kernel 6: fused serial reduce + parallel pack ----------------
// Serial feed fix (R13): the diagonal words are chain-invariant, so they are
// pulled into VGPRs via an explicit group-pipelined register feed: dbuf/dnxt
// arrays of 16, group g+1's independent ds_reads issued BEFORE group g's VALU
// steps — one lgkmcnt wait per chunk instead of one per rank. (__shfl is
// ds_bpermute = LDS latency; that's why R9's shfl feed stayed at ~55 µs.)
__device__ __forceinline__ void nms_chunk_body(
    int c, int nchunk, int lane, int g, int w,
    const ull* __restrict__ mrow, ull* sm,
    ull (&pr)[16], ull (&st)[16], ull& S)
{
    int cb = (c & 1) << 10;
    int nb = ((c + 1) & 1) << 10;
    if (c + 2 < nchunk) {                    // prefetch chunk c+2 from global
        #pragma unroll
        for (int k = 0; k < 16; ++k)
            pr[k] = mrow[(size_t)(c + 2) * 1024 + k * 64 + lane];
    }

    // ---- serial greedy on word c: register-fed, group-pipelined ----
    ull cur = __shfl(S, c);
    ull dbuf[16], dnxt[16];
    #pragma unroll
    for (int k = 0; k < 16; ++k) dbuf[k] = sm[cb + (k << 4) + c];   // group 0
    #pragma unroll
    for (int grp = 0; grp < 4; ++grp) {
        if (grp < 3) {                       // issue group grp+1 reads (independent)
            #pragma unroll
            for (int k = 0; k < 16; ++k)
                dnxt[k] = sm[cb + ((((grp + 1) << 4) + k) << 4) + c];
        }
        #pragma unroll
        for (int k = 0; k < 16; ++k) {       // pure-VALU serial steps
            int i = (grp << 4) + k;
            ull supm = (ull)((long long)(cur << (63 - i)) >> 63);   // all-ones iff rank i suppressed
            cur |= dbuf[k] & ~supm;
        }
        if (grp < 3) {
            #pragma unroll
            for (int k = 0; k < 16; ++k) dbuf[k] = dnxt[k];
        }
    }
    ull kbits = ~cur;                        // kept = not suppressed

    // ---- bulk apply: lane (g,w) ORs kept rows of group g, word w ----
    unsigned sub = (unsigned)((kbits >> (g << 4)) & 0xFFFFull);
    int rbase2 = cb + (g << 8) + w;
    ull part = 0ull;
    #pragma unroll
    for (int i = 0; i < 16; ++i) {
        ull v = sm[rbase2 + (i << 4)];       // unconditional, pipelined
        part |= v & (ull)(0ll - (long long)((sub >> i) & 1u));
    }
    part |= __shfl_xor(part, 16);
    part |= __shfl_xor(part, 32);
    S |= part;                               // lanes 0..15 meaningful
    if (lane == c) S = cur;                  // finalize word c

    if (c + 1 < nchunk) {                    // stage chunk c+1 into the other LDS buffer
        #pragma unroll
        for (int k = 0; k < 16; ++k) sm[nb + k * 64 + lane] = st[k];
    }
}

__global__ void __launch_bounds__(256)
reduce_pack_kernel(const ull* __restrict__ mask,
                   const int* __restrict__ nselArr,
                   const float* __restrict__ rows,
                   float* __restrict__ out) {
    int bc  = blockIdx.x;
    int tid = threadIdx.x;
    int nsel = nselArr[bc];
    const ull* mrow = mask + ((size_t)bc * ROWS << 4);

    __shared__ ull sm[2048];                // 2 x (64 rows x 16 words) = 16 KB
    __shared__ ull kw[WORDS];
    __shared__ unsigned pref[WORDS + 1];

    if (tid < 64) {                          // wave 0: serial reduce
        int lane = tid;
        int nchunk = (nsel + 63) >> 6;       // <= 16
        ull S = 0ull;
        int g = lane >> 4;
        int w = lane & 15;

        ull ra[16], rb[16];
        if (nchunk > 0) {
            #pragma unroll
            for (int k = 0; k < 16; ++k) ra[k] = mrow[k * 64 + lane];
            if (nchunk > 1) {
                #pragma unroll
                for (int k = 0; k < 16; ++k) rb[k] = mrow[1024 + k * 64 + lane];
            }
            #pragma unroll
            for (int k = 0; k < 16; ++k) sm[k * 64 + lane] = ra[k];

            #pragma unroll 1
            for (int cc = 0; cc < 8; ++cc) {
                int c0 = cc << 1;
                if (c0 >= nchunk) break;
                nms_chunk_body(c0, nchunk, lane, g, w, mrow, sm, ra, rb, S);
                int c1 = c0 + 1;
                if (c1 >= nchunk) break;
                nms_chunk_body(c1, nchunk, lane, g, w, mrow, sm, rb, ra, S);
            }
        }

        if (lane < WORDS) {
            int base_i = lane << 6;
            ull valid = 0ull;
            int rem = nsel - base_i;
            if (rem > 0) valid = (rem >= 64) ? ~0ull : ((1ull << rem) - 1ull);
            kw[lane] = (~S) & valid;
        }
    }
    __syncthreads();

    if (tid == 0) {
        unsigned c = 0;
        for (int w = 0; w < WORDS; ++w) { pref[w] = c; c += (unsigned)__popcll(kw[w]); }
        pref[WORDS] = c;
    }
    __syncthreads();
    unsigned tot = pref[WORDS];

    const float* rbase = rows + (size_t)bc * KTOP * 5;
    float* obase = out + (size_t)bc * KTOP * 5;
    for (int r = tid; r < KTOP; r += 256) {
        ull wv = kw[r >> 6];
        if ((wv >> (r & 63)) & 1ull) {
            int pos = (int)pref[r >> 6] + __popcll(wv & ((1ull << (r & 63)) - 1ull));
            const float* rr = rbase + r * 5;
            float* oo = obase + pos * 5;
            oo[0] = rr[0]; oo[1] = rr[1]; oo[2] = rr[2]; oo[3] = rr[3]; oo[4] = rr[4];
        }
        if (r >= (int)tot) {                 // zero-fill tail (replaces out memset)
            float* oo = obase + r * 5;
            oo[0] = 0.f; oo[1] = 0.f; oo[2] = 0.f; oo[3] = 0.f; oo[4] = 0.f;
        }
    }
}

// ------------------------------- launcher -------------------------------
extern "C" void kernel_launch(void* const* d_in, const int* in_sizes, int n_in,
                              void* d_out, int out_size, void* d_ws, size_t ws_size,
                              hipStream_t stream) {
    (void)n_in; (void)out_size; (void)ws_size;
    const float* loc   = (const float*)d_in[0];
    const float* conf  = (const float*)d_in[1];
    const float* prior = (const float*)d_in[2];
    const float* cth   = (const float*)d_in[3];
    const float* nth   = (const float*)d_in[4];
    float* out = (float*)d_out;

    int P   = in_sizes[2] / 4;
    int B   = in_sizes[0] / (4 * P);
    int C   = in_sizes[1] / (B * P);
    int Cfg = C - 1;
    int NBC = B * Cfg;

    // ---- carve workspace (256B aligned sections; widest types first) ----
    char* base = (char*)d_ws;
    size_t off = 0;
    auto carve = [&](size_t bytes) { char* p = base + off; off = (off + bytes + 255) & ~(size_t)255; return p; };

    float4*   pbox   = (float4*)  carve((size_t)NBC * ROWS * 16);
    ull*      cand   = (ull*)     carve((size_t)NBC * CAP * 8);
    ull*      mask   = (ull*)     carve((size_t)NBC * ROWS * WORDS * 8);
    float*    scores = (float*)   carve((size_t)NBC * P * 4);
    float*    cs     = (float*)   carve((size_t)B * P * 4 * 4);
    float*    rows   = (float*)   carve((size_t)NBC * KTOP * 5 * 4);
    float*    bar    = (float*)   carve((size_t)NBC * ROWS * 4);
    unsigned* hist   = (unsigned*)carve((size_t)NBC * HB * 4 + (size_t)NBC * 4);  // hist + cnt contiguous
    unsigned* cnt    = hist + (size_t)NBC * HB;
    unsigned* pivot  = (unsigned*)carve((size_t)NBC * 4);
    int*      nselA  = (int*)     carve((size_t)NBC * 4);

    int histW = NBC * HB + NBC;              // words to zero (hist + cnt)

    int n1 = B * P;
    decode_kernel<<<(n1 + 255) / 256, 256, 0, stream>>>(loc, conf, prior, scores, cs, hist, histW, B, C, P);
    hist_kernel<<<dim3(NBC, HCHUNK), 256, 0, stream>>>(scores, cth, hist, P);
    pivot_kernel<<<NBC, 256, 0, stream>>>(hist, pivot);
    gather_kernel<<<dim3(NBC, 32), 256, 0, stream>>>(scores, pivot, cnt, cand, cth, P);
    sort_kernel<<<NBC, 1024, 0, stream>>>(cand, cnt, cs, rows, pbox, bar, nselA, P, Cfg);
    mask_kernel<<<dim3(NBC, ROWS / 64), 1024, 0, stream>>>(pbox, bar, nselA, nth, mask);
    reduce_pack_kernel<<<NBC, 256, 0, stream>>>(mask, nselA, rows, out);
}